// Round 3
// baseline (812.992 us; speedup 1.0000x reference)
//
#include <hip/hip_runtime.h>

// ---------------- problem constants ----------------
#define B_    2
#define S_    1024
#define H_    1024
#define NH_   16
#define HD_   64
#define SE_   512
#define E_    1024
#define NEXP_ 8
#define FF_   2048
#define T_    (B_*S_)    // 2048 tokens
#define TE_   (B_*SE_)   // 1024 encoder tokens
#define PERM_MAX 4608
#define MAXRT 72

typedef short v8s __attribute__((ext_vector_type(8)));
typedef short v4s __attribute__((ext_vector_type(4)));
typedef float v4f __attribute__((ext_vector_type(4)));
typedef _Float16 v8h __attribute__((ext_vector_type(8)));

__device__ __forceinline__ unsigned short f2b(float f) {
  unsigned int u = __float_as_uint(f);
  u = (u + 0x7FFFu + ((u >> 16) & 1u)) >> 16;   // RNE f32 -> bf16 bits
  return (unsigned short)u;
}
__device__ __forceinline__ float b2f(unsigned short h) {
  return __uint_as_float(((unsigned int)h) << 16);
}

// ---------------- int64-vs-int32 ABI detect ----------------
__global__ void detect_kern(const int* __restrict__ pos, const int* __restrict__ msk,
                            int* __restrict__ flags) {
  if (threadIdx.x == 0) {
    flags[0] = (pos[1] == 1) ? 0 : 1;
    flags[1] = (msk[1] == 1) ? 0 : 1;
  }
}

// ---------------- RMSNorm f32 -> f32 ----------------
__global__ __launch_bounds__(256)
void rmsnorm_f32_kern(const float* __restrict__ x, const float* __restrict__ w,
                      float* __restrict__ y) {
  int row = blockIdx.x, tid = threadIdx.x;
  const float* xr = x + (long)row * 1024;
  v4f v = *(const v4f*)&xr[tid * 4];
  float ss = v[0]*v[0] + v[1]*v[1] + v[2]*v[2] + v[3]*v[3];
  #pragma unroll
  for (int off = 32; off; off >>= 1) ss += __shfl_xor(ss, off);
  __shared__ float sw[4];
  if ((tid & 63) == 0) sw[tid >> 6] = ss;
  __syncthreads();
  float tot = sw[0] + sw[1] + sw[2] + sw[3];
  float rs = rsqrtf(tot * (1.0f / 1024.0f) + 1e-6f);
  const float* wr = w + tid * 4;
  v4f o;
  #pragma unroll
  for (int j = 0; j < 4; ++j) o[j] = v[j] * rs * wr[j];
  *(v4f*)&y[(long)row * 1024 + tid * 4] = o;
}

// ---------------- RMSNorm f32 -> bf16 (MoE h3) ----------------
__global__ __launch_bounds__(256)
void rmsnorm_kern(const float* __restrict__ x, const float* __restrict__ w,
                  unsigned short* __restrict__ y) {
  int row = blockIdx.x, tid = threadIdx.x;
  const float* xr = x + (long)row * 1024;
  v4f v = *(const v4f*)&xr[tid * 4];
  float ss = v[0]*v[0] + v[1]*v[1] + v[2]*v[2] + v[3]*v[3];
  #pragma unroll
  for (int off = 32; off; off >>= 1) ss += __shfl_xor(ss, off);
  __shared__ float sw[4];
  if ((tid & 63) == 0) sw[tid >> 6] = ss;
  __syncthreads();
  float tot = sw[0] + sw[1] + sw[2] + sw[3];
  float rs = rsqrtf(tot * (1.0f / 1024.0f) + 1e-6f);
  const float* wr = w + tid * 4;
  v4s o;
  #pragma unroll
  for (int j = 0; j < 4; ++j) o[j] = (short)f2b(v[j] * rs * wr[j]);
  *(v4s*)&y[(long)row * 1024 + tid * 4] = o;
}

// ---------------- RoPE in-place on f32 q,k ----------------
__global__ __launch_bounds__(256)
void rope_f32_kern(float* __restrict__ q, float* __restrict__ k,
                   const int* __restrict__ pos, const int* __restrict__ flags) {
  int g = blockIdx.x * 256 + threadIdx.x;
  int d = g & 31;
  int h = (g >> 5) & 15;
  int s = (g >> 9) & (S_ - 1);
  int b = g >> 19;
  long base = (((long)(b * S_ + s)) * NH_ + h) * HD_;
  int pidx = b * S_ + s;
  int pv = pos[flags[0] ? (pidx << 1) : pidx];
  float p = (float)pv;
  float inv = powf(10000.0f, -(float)d * (1.0f / 32.0f));
  float f = p * inv;
  float sn = sinf(f), cs = cosf(f);
  float q1 = q[base + d], q2 = q[base + d + 32];
  q[base + d]      = q1 * cs - q2 * sn;
  q[base + d + 32] = q2 * cs + q1 * sn;
  float k1 = k[base + d], k2 = k[base + d + 32];
  k[base + d]      = k1 * cs - k2 * sn;
  k[base + d + 32] = k2 * cs + k1 * sn;
}

// ---------------- high-precision GEMM: C[M,N] = A[M,K]f32 @ B[N,K]f32^T
// split-fp16 3-pass (hi*hi + hi*lo + lo*hi), f32 accumulate.
// EPI: 0: C=acc | 2: C=(acc+bias)*scale | 3: C=resid+acc(+bias)
template<int EPI>
__global__ __launch_bounds__(256)
void gemm_f32(const float* __restrict__ A, int lda,
              const float* __restrict__ B, int ldb,
              const float* __restrict__ bias, const float* __restrict__ resid,
              float scale,
              float* __restrict__ Cf, int ldc, int K) {
  int row0 = blockIdx.x * 64, col0 = blockIdx.y * 64;
  int tid = threadIdx.x, lane = tid & 63, wid = tid >> 6;
  int wr = wid >> 1, wc = wid & 1;
  int lr = lane & 15, lg = lane >> 4;

  __shared__ _Float16 Ah[64][40], Al[64][40], Bh[64][40], Bl[64][40];

  v4f acc[2][2] = {};
  int ar = tid >> 2, ac = (tid & 3) * 8;
  const float* Ap = A + (long)(row0 + ar) * lda + ac;
  const float* Bp = B + (long)(col0 + ar) * ldb + ac;

  for (int k0 = 0; k0 < K; k0 += 32) {
    __syncthreads();
    v4f a0 = *(const v4f*)&Ap[k0];
    v4f a1 = *(const v4f*)&Ap[k0 + 4];
    v4f b0 = *(const v4f*)&Bp[k0];
    v4f b1 = *(const v4f*)&Bp[k0 + 4];
    v8h ahv, alv, bhv, blv;
    #pragma unroll
    for (int j = 0; j < 8; ++j) {
      float av = j < 4 ? a0[j] : a1[j - 4];
      _Float16 hh = (_Float16)av;
      ahv[j] = hh; alv[j] = (_Float16)(av - (float)hh);
      float bv = j < 4 ? b0[j] : b1[j - 4];
      hh = (_Float16)bv;
      bhv[j] = hh; blv[j] = (_Float16)(bv - (float)hh);
    }
    *(v8h*)&Ah[ar][ac] = ahv;
    *(v8h*)&Al[ar][ac] = alv;
    *(v8h*)&Bh[ar][ac] = bhv;
    *(v8h*)&Bl[ar][ac] = blv;
    __syncthreads();

    v8h ah[2], al2[2], bh[2], bl2[2];
    #pragma unroll
    for (int m = 0; m < 2; ++m) {
      ah[m]  = *(const v8h*)&Ah[wr*32 + m*16 + lr][lg*8];
      al2[m] = *(const v8h*)&Al[wr*32 + m*16 + lr][lg*8];
    }
    #pragma unroll
    for (int n = 0; n < 2; ++n) {
      bh[n]  = *(const v8h*)&Bh[wc*32 + n*16 + lr][lg*8];
      bl2[n] = *(const v8h*)&Bl[wc*32 + n*16 + lr][lg*8];
    }
    #pragma unroll
    for (int m = 0; m < 2; ++m)
      #pragma unroll
      for (int n = 0; n < 2; ++n) {
        acc[m][n] = __builtin_amdgcn_mfma_f32_16x16x32_f16(ah[m],  bh[n],  acc[m][n], 0, 0, 0);
        acc[m][n] = __builtin_amdgcn_mfma_f32_16x16x32_f16(ah[m],  bl2[n], acc[m][n], 0, 0, 0);
        acc[m][n] = __builtin_amdgcn_mfma_f32_16x16x32_f16(al2[m], bh[n],  acc[m][n], 0, 0, 0);
      }
  }

  #pragma unroll
  for (int m = 0; m < 2; ++m) {
    int rl = wr * 32 + m * 16 + lg * 4;
    #pragma unroll
    for (int n = 0; n < 2; ++n) {
      int gcol = col0 + wc * 32 + n * 16 + lr;
      #pragma unroll
      for (int rr = 0; rr < 4; ++rr) {
        int grow = row0 + rl + rr;
        float v = acc[m][n][rr];
        if constexpr (EPI == 0) {
          Cf[(long)grow * ldc + gcol] = v;
        } else if constexpr (EPI == 2) {
          Cf[(long)grow * ldc + gcol] = (v + bias[gcol]) * scale;
        } else if constexpr (EPI == 3) {
          float bb = bias ? bias[gcol] : 0.0f;
          Cf[(long)grow * ldc + gcol] = resid[(long)grow * ldc + gcol] + v + bb;
        }
      }
    }
  }
}

// ---------------- flash attention, split-fp16 3-pass, f32 in/out ----------
template<bool CAUSAL>
__global__ __launch_bounds__(256)
void attn_split(const float* __restrict__ Q, const float* __restrict__ Kp,
                const float* __restrict__ Vp, float* __restrict__ O,
                const int* __restrict__ mask, const int* __restrict__ flags,
                int Sq, int Sk, float qscale) {
  int qt = blockIdx.x, bh = blockIdx.y;
  int b = bh >> 4, h = bh & 15;
  int tid = threadIdx.x, lane = tid & 63, w = tid >> 6;
  int lr = lane & 15, lg = lane >> 4;
  int q0 = qt * 64;
  int mf = (!CAUSAL && mask) ? flags[1] : 0;

  __shared__ _Float16 Kh[64][72], Kl[64][72];
  __shared__ _Float16 Vh[64][72], Vl[64][72];     // transposed [d][key]
  __shared__ _Float16 Psh[4][16][72], Psl[4][16][72];

  v8h qh[2], ql[2];
  {
    long qbase = ((long)(b * Sq + q0 + w * 16 + lr) * NH_ + h) * HD_;
    #pragma unroll
    for (int kk = 0; kk < 2; ++kk) {
      v4f f0 = *(const v4f*)&Q[qbase + kk * 32 + lg * 8];
      v4f f1 = *(const v4f*)&Q[qbase + kk * 32 + lg * 8 + 4];
      #pragma unroll
      for (int j = 0; j < 8; ++j) {
        float f = (j < 4 ? f0[j] : f1[j - 4]) * qscale;
        _Float16 hh = (_Float16)f;
        qh[kk][j] = hh;
        ql[kk][j] = (_Float16)(f - (float)hh);
      }
    }
  }
  v4f of[4] = {};
  float m4[4], l4[4];
  #pragma unroll
  for (int i = 0; i < 4; ++i) { m4[i] = -3e38f; l4[i] = 0.0f; }

  int nkt = CAUSAL ? (qt + 1) : (Sk >> 6);
  for (int kt = 0; kt < nkt; ++kt) {
    __syncthreads();
    #pragma unroll
    for (int i = 0; i < 2; ++i) {
      int idx = tid + i * 256;
      int r = idx >> 3, c = (idx & 7) * 8;
      long gb = ((long)(b * Sk + kt * 64 + r) * NH_ + h) * HD_ + c;
      v4f k0v = *(const v4f*)&Kp[gb];
      v4f k1v = *(const v4f*)&Kp[gb + 4];
      v4f v0v = *(const v4f*)&Vp[gb];
      v4f v1v = *(const v4f*)&Vp[gb + 4];
      v8h khv, klv;
      #pragma unroll
      for (int j = 0; j < 8; ++j) {
        float kf = j < 4 ? k0v[j] : k1v[j - 4];
        _Float16 hh = (_Float16)kf;
        khv[j] = hh; klv[j] = (_Float16)(kf - (float)hh);
        float vf = j < 4 ? v0v[j] : v1v[j - 4];
        hh = (_Float16)vf;
        Vh[c + j][r] = hh; Vl[c + j][r] = (_Float16)(vf - (float)hh);
      }
      *(v8h*)&Kh[r][c] = khv;
      *(v8h*)&Kl[r][c] = klv;
    }
    __syncthreads();

    v4f sf[4] = {};
    #pragma unroll
    for (int kk = 0; kk < 2; ++kk)
      #pragma unroll
      for (int n = 0; n < 4; ++n) {
        v8h kbh = *(const v8h*)&Kh[n * 16 + lr][kk * 32 + lg * 8];
        v8h kbl = *(const v8h*)&Kl[n * 16 + lr][kk * 32 + lg * 8];
        sf[n] = __builtin_amdgcn_mfma_f32_16x16x32_f16(qh[kk], kbh, sf[n], 0, 0, 0);
        sf[n] = __builtin_amdgcn_mfma_f32_16x16x32_f16(qh[kk], kbl, sf[n], 0, 0, 0);
        sf[n] = __builtin_amdgcn_mfma_f32_16x16x32_f16(ql[kk], kbh, sf[n], 0, 0, 0);
      }

    if constexpr (CAUSAL) {
      if (kt == qt) {
        #pragma unroll
        for (int n = 0; n < 4; ++n) {
          int kcol = kt * 64 + n * 16 + lr;
          #pragma unroll
          for (int rr = 0; rr < 4; ++rr) {
            int qr = q0 + w * 16 + lg * 4 + rr;
            if (kcol > qr) sf[n][rr] = -1e9f;
          }
        }
      }
    } else {
      if (mask) {
        #pragma unroll
        for (int n = 0; n < 4; ++n) {
          int kcol = kt * 64 + n * 16 + lr;
          int mi = b * Sk + kcol;
          if (mask[mf ? (mi << 1) : mi] == 0) {
            #pragma unroll
            for (int rr = 0; rr < 4; ++rr) sf[n][rr] = -1e9f;
          }
        }
      }
    }

    float al[4];
    #pragma unroll
    for (int rr = 0; rr < 4; ++rr) {
      float mx = fmaxf(fmaxf(sf[0][rr], sf[1][rr]), fmaxf(sf[2][rr], sf[3][rr]));
      #pragma unroll
      for (int off = 8; off; off >>= 1) mx = fmaxf(mx, __shfl_xor(mx, off));
      float mn = fmaxf(m4[rr], mx);
      al[rr] = __expf(m4[rr] - mn);
      m4[rr] = mn;
      float rs = 0.0f;
      #pragma unroll
      for (int n = 0; n < 4; ++n) {
        float pv = __expf(sf[n][rr] - mn);
        sf[n][rr] = pv;
        rs += pv;
      }
      #pragma unroll
      for (int off = 8; off; off >>= 1) rs += __shfl_xor(rs, off);
      l4[rr] = l4[rr] * al[rr] + rs;
    }

    #pragma unroll
    for (int n = 0; n < 4; ++n)
      #pragma unroll
      for (int rr = 0; rr < 4; ++rr) {
        of[n][rr] *= al[rr];
        float pv = sf[n][rr];
        _Float16 ph = (_Float16)pv;
        Psh[w][lg * 4 + rr][n * 16 + lr] = ph;
        Psl[w][lg * 4 + rr][n * 16 + lr] = (_Float16)(pv - (float)ph);
      }
    __syncthreads();

    #pragma unroll
    for (int kc = 0; kc < 2; ++kc) {
      v8h pah = *(const v8h*)&Psh[w][lr][kc * 32 + lg * 8];
      v8h pal = *(const v8h*)&Psl[w][lr][kc * 32 + lg * 8];
      #pragma unroll
      for (int n = 0; n < 4; ++n) {
        v8h vbh = *(const v8h*)&Vh[n * 16 + lr][kc * 32 + lg * 8];
        v8h vbl = *(const v8h*)&Vl[n * 16 + lr][kc * 32 + lg * 8];
        of[n] = __builtin_amdgcn_mfma_f32_16x16x32_f16(pah, vbh, of[n], 0, 0, 0);
        of[n] = __builtin_amdgcn_mfma_f32_16x16x32_f16(pah, vbl, of[n], 0, 0, 0);
        of[n] = __builtin_amdgcn_mfma_f32_16x16x32_f16(pal, vbh, of[n], 0, 0, 0);
      }
    }
  }

  #pragma unroll
  for (int rr = 0; rr < 4; ++rr) {
    int qr = q0 + w * 16 + lg * 4 + rr;
    float inv = 1.0f / l4[rr];
    long ob = (long)(b * Sq + qr) * 1024 + h * 64;
    #pragma unroll
    for (int n = 0; n < 4; ++n) O[ob + n * 16 + lr] = of[n][rr] * inv;
  }
}

// ---------------- MoE bf16 GEMM (gathered):  EPI 4 swiglu | 5 scatter-acc ----
template<int EPI, bool AGATHER>
__global__ __launch_bounds__(256)
void gemm_bt(const unsigned short* __restrict__ A, int lda,
             const float* __restrict__ B1, const float* __restrict__ B2,
             int ldb, long bstride,
             float* __restrict__ Cf, unsigned short* __restrict__ Cb, int ldc,
             const int* __restrict__ tm_e, const int* __restrict__ tm_slot,
             const int* __restrict__ ntl,
             const int* __restrict__ perm, const float* __restrict__ pwgt,
             int K) {
  int tile = blockIdx.x;
  if (tile >= ntl[0]) return;
  int e = tm_e[tile];
  int row0 = tm_slot[tile];
  const float* Bp = B1 + (long)e * bstride;
  const float* Bp2 = (EPI == 4) ? (B2 + (long)e * bstride) : nullptr;
  int col0 = blockIdx.y * 64;
  int tid = threadIdx.x;
  int lane = tid & 63, wid = tid >> 6;
  int wr = wid >> 1, wc = wid & 1;
  int lr = lane & 15, lg = lane >> 4;

  __shared__ unsigned short As[64][40];
  __shared__ unsigned short Bs[64][40];
  __shared__ unsigned short Bs2[(EPI == 4) ? 64 : 1][40];

  v4f acc[2][2] = {};
  v4f acc2[2][2] = {};

  int ar = tid >> 2;
  int ac = (tid & 3) * 8;
  long arow;
  bool aok = true;
  if constexpr (AGATHER) {
    int tok = perm[row0 + ar];
    aok = (tok >= 0);
    arow = (long)(aok ? tok : 0) * lda;
  } else {
    arow = (long)(row0 + ar) * lda;
  }

  for (int k0 = 0; k0 < K; k0 += 32) {
    __syncthreads();
    v8s av = {};
    if (aok) av = *(const v8s*)&A[arow + k0 + ac];
    *(v8s*)&As[ar][ac] = av;
    #pragma unroll
    for (int i = 0; i < 2; ++i) {
      int idx = tid + i * 256;
      int br = idx >> 3, bc = (idx & 7) * 4;
      v4f bv = *(const v4f*)&Bp[(long)(col0 + br) * ldb + k0 + bc];
      v4s h4;
      #pragma unroll
      for (int j = 0; j < 4; ++j) h4[j] = (short)f2b(bv[j]);
      *(v4s*)&Bs[br][bc] = h4;
      if constexpr (EPI == 4) {
        v4f b2v = *(const v4f*)&Bp2[(long)(col0 + br) * ldb + k0 + bc];
        v4s h42;
        #pragma unroll
        for (int j = 0; j < 4; ++j) h42[j] = (short)f2b(b2v[j]);
        *(v4s*)&Bs2[br][bc] = h42;
      }
    }
    __syncthreads();
    int ko = lg * 8;
    v8s a[2], b[2];
    #pragma unroll
    for (int m = 0; m < 2; ++m) a[m] = *(const v8s*)&As[wr * 32 + m * 16 + lr][ko];
    #pragma unroll
    for (int n = 0; n < 2; ++n) b[n] = *(const v8s*)&Bs[wc * 32 + n * 16 + lr][ko];
    #pragma unroll
    for (int m = 0; m < 2; ++m)
      #pragma unroll
      for (int n = 0; n < 2; ++n)
        acc[m][n] = __builtin_amdgcn_mfma_f32_16x16x32_bf16(a[m], b[n], acc[m][n], 0, 0, 0);
    if constexpr (EPI == 4) {
      v8s c2[2];
      #pragma unroll
      for (int n = 0; n < 2; ++n) c2[n] = *(const v8s*)&Bs2[wc * 32 + n * 16 + lr][ko];
      #pragma unroll
      for (int m = 0; m < 2; ++m)
        #pragma unroll
        for (int n = 0; n < 2; ++n)
          acc2[m][n] = __builtin_amdgcn_mfma_f32_16x16x32_bf16(a[m], c2[n], acc2[m][n], 0, 0, 0);
    }
  }

  #pragma unroll
  for (int m = 0; m < 2; ++m) {
    int rl = wr * 32 + m * 16 + lg * 4;
    #pragma unroll
    for (int n = 0; n < 2; ++n) {
      int gcol = col0 + wc * 32 + n * 16 + lr;
      #pragma unroll
      for (int rr = 0; rr < 4; ++rr) {
        int grow = row0 + rl + rr;
        float v = acc[m][n][rr];
        if constexpr (EPI == 4) {
          float g = v / (1.0f + __expf(-v));           // silu
          Cb[(long)grow * ldc + gcol] = f2b(g * acc2[m][n][rr]);
        } else if constexpr (EPI == 5) {
          int tok = perm[grow];
          if (tok >= 0) atomicAdd(&Cf[(long)tok * ldc + gcol], v * pwgt[grow]);
        }
      }
    }
  }
}

// ---------------- MoE router: f32 rms + logits + top-2 ----------------
__global__ __launch_bounds__(64)
void router_kern(const float* __restrict__ x, const float* __restrict__ w,
                 const float* __restrict__ gw,
                 int* __restrict__ topi, float* __restrict__ topw,
                 int* __restrict__ counts) {
  int t = blockIdx.x, lane = threadIdx.x;
  const float* xr = x + (long)t * 1024;
  float vals[16];
  float ss = 0.0f;
  #pragma unroll
  for (int i = 0; i < 16; ++i) { float v = xr[lane + i * 64]; vals[i] = v; ss += v * v; }
  #pragma unroll
  for (int off = 32; off; off >>= 1) ss += __shfl_xor(ss, off);
  float rs = rsqrtf(ss * (1.0f / 1024.0f) + 1e-6f);
  #pragma unroll
  for (int i = 0; i < 16; ++i) vals[i] *= rs * w[lane + i * 64];
  float lgts[8];
  #pragma unroll
  for (int e = 0; e < 8; ++e) {
    const float* g = gw + e * 1024;
    float s = 0.0f;
    #pragma unroll
    for (int i = 0; i < 16; ++i) s += vals[i] * g[lane + i * 64];
    #pragma unroll
    for (int off = 32; off; off >>= 1) s += __shfl_xor(s, off);
    lgts[e] = s;
  }
  int i1 = 0; float l1 = lgts[0];
  #pragma unroll
  for (int e = 1; e < 8; ++e) if (lgts[e] > l1) { l1 = lgts[e]; i1 = e; }
  int i2 = -1; float l2 = -3e38f;
  #pragma unroll
  for (int e = 0; e < 8; ++e) if (e != i1 && lgts[e] > l2) { l2 = lgts[e]; i2 = e; }
  float w1 = 1.0f / (1.0f + __expf(l2 - l1));
  if (lane == 0) {
    topi[t * 2] = i1; topi[t * 2 + 1] = i2;
    topw[t * 2] = w1; topw[t * 2 + 1] = 1.0f - w1;
    atomicAdd(&counts[i1], 1);
    atomicAdd(&counts[i2], 1);
  }
}

__global__ __launch_bounds__(256)
void finalize_kern(const int* __restrict__ counts, int* __restrict__ poff,
                   int* __restrict__ tm_e, int* __restrict__ tm_slot,
                   int* __restrict__ ntl, int* __restrict__ perm) {
  __shared__ int stot;
  if (threadIdx.x == 0) {
    int off = 0, nt = 0;
    for (int e = 0; e < 8; ++e) {
      poff[e] = off;
      int c = counts[e];
      int ntE = (c + 63) >> 6;
      for (int i = 0; i < ntE; ++i) { tm_e[nt] = e; tm_slot[nt] = off + i * 64; ++nt; }
      off += ntE * 64;
    }
    ntl[0] = nt; ntl[1] = off;
    stot = off;
  }
  __syncthreads();
  for (int s = threadIdx.x; s < stot; s += 256) perm[s] = -1;
}

__global__ __launch_bounds__(256)
void scatter_kern(const int* __restrict__ topi, const float* __restrict__ topw,
                  const int* __restrict__ poff, int* __restrict__ cursor,
                  int* __restrict__ perm, float* __restrict__ pwgt) {
  int t = blockIdx.x * 256 + threadIdx.x;
  if (t >= T_) return;
  #pragma unroll
  for (int kk = 0; kk < 2; ++kk) {
    int e = topi[t * 2 + kk];
    int pos = atomicAdd(&cursor[e], 1);
    int slot = poff[e] + pos;
    perm[slot] = t;
    pwgt[slot] = topw[t * 2 + kk];
  }
}

// ---------------- host launcher ----------------
extern "C" void kernel_launch(void* const* d_in, const int* in_sizes, int n_in,
                              void* d_out, int out_size, void* d_ws, size_t ws_size,
                              hipStream_t stream) {
  (void)in_sizes; (void)n_in; (void)out_size; (void)ws_size;
  const float* x_in  = (const float*)d_in[0];
  const int*  posids = (const int*)d_in[1];
  const float* enc   = (const float*)d_in[2];
  const int*  emask  = (const int*)d_in[3];
  const float* inln  = (const float*)d_in[4];
  const float* wq    = (const float*)d_in[5];
  const float* wk    = (const float*)d_in[6];
  const float* wv    = (const float*)d_in[7];
  const float* wo    = (const float*)d_in[8];
  const float* cnorm = (const float*)d_in[9];
  const float* cqw   = (const float*)d_in[10];
  const float* cqb   = (const float*)d_in[11];
  const float* ckw   = (const float*)d_in[12];
  const float* ckb   = (const float*)d_in[13];
  const float* cvw   = (const float*)d_in[14];
  const float* cvb   = (const float*)d_in[15];
  const float* cow   = (const float*)d_in[16];
  const float* cob   = (const float*)d_in[17];
  const float* pln   = (const float*)d_in[18];
  const float* gatew = (const float*)d_in[19];
  const float* w1    = (const float*)d_in[20];
  const float* w2    = (const float*)d_in[21];
  const float* w3    = (const float*)d_in[22];
  float* out = (float*)d_out;

  char* p = (char*)d_ws;
  auto alloc = [&](size_t bytes) -> char* {
    char* r = p;
    p += (bytes + 255) & ~(size_t)255;
    return r;
  };
  float* h    = (float*)alloc((size_t)T_ * H_ * 4);
  float* qf   = (float*)alloc((size_t)T_ * H_ * 4);
  float* kf   = (float*)alloc((size_t)T_ * H_ * 4);
  float* vf   = (float*)alloc((size_t)T_ * H_ * 4);
  float* of   = (float*)alloc((size_t)T_ * H_ * 4);
  float* x1   = (float*)alloc((size_t)T_ * H_ * 4);
  float* h2   = (float*)alloc((size_t)T_ * H_ * 4);
  float* cqf  = (float*)alloc((size_t)T_ * H_ * 4);
  float* ckf  = (float*)alloc((size_t)TE_ * H_ * 4);
  float* cvf  = (float*)alloc((size_t)TE_ * H_ * 4);
  float* cof  = (float*)alloc((size_t)T_ * H_ * 4);
  float* x2   = (float*)alloc((size_t)T_ * H_ * 4);
  unsigned short* h3b = (unsigned short*)alloc((size_t)T_ * H_ * 2);
  int*   meta    = (int*)alloc(4 * (8 + 8 + 8 + 2 + 2 + MAXRT + MAXRT));
  int*   counts  = meta;
  int*   cursor  = meta + 8;
  int*   poff    = meta + 16;
  int*   ntl     = meta + 24;
  int*   flags   = meta + 26;
  int*   tm_e    = meta + 28;
  int*   tm_slot = meta + 28 + MAXRT;
  int*   topi    = (int*)alloc((size_t)T_ * 2 * 4);
  float* topw    = (float*)alloc((size_t)T_ * 2 * 4);
  int*   perm    = (int*)alloc((size_t)PERM_MAX * 4);
  float* pwgt    = (float*)alloc((size_t)PERM_MAX * 4);
  unsigned short* ffh = (unsigned short*)alloc((size_t)PERM_MAX * FF_ * 2);

  dim3 blk(256);

  detect_kern<<<1, 64, 0, stream>>>(posids, emask, flags);

  // ---- self-attention block ----
  rmsnorm_f32_kern<<<T_, blk, 0, stream>>>(x_in, inln, h);
  gemm_f32<0><<<dim3(32, 16), blk, 0, stream>>>(h, 1024, wq, 1024, nullptr, nullptr, 1.0f, qf, 1024, 1024);
  gemm_f32<0><<<dim3(32, 16), blk, 0, stream>>>(h, 1024, wk, 1024, nullptr, nullptr, 1.0f, kf, 1024, 1024);
  gemm_f32<0><<<dim3(32, 16), blk, 0, stream>>>(h, 1024, wv, 1024, nullptr, nullptr, 1.0f, vf, 1024, 1024);
  rope_f32_kern<<<(B_ * S_ * NH_ * 32) / 256, blk, 0, stream>>>(qf, kf, posids, flags);
  attn_split<true><<<dim3(S_ / 64, B_ * NH_), blk, 0, stream>>>(
      qf, kf, vf, of, nullptr, flags, S_, S_, 0.125f);
  gemm_f32<3><<<dim3(32, 16), blk, 0, stream>>>(of, 1024, wo, 1024, nullptr, x_in, 1.0f, x1, 1024, 1024);

  // ---- cross-attention block ----
  rmsnorm_f32_kern<<<T_, blk, 0, stream>>>(x1, cnorm, h2);
  gemm_f32<2><<<dim3(32, 16), blk, 0, stream>>>(h2, 1024, cqw, 1024, cqb, nullptr, 1.0f, cqf, 1024, 1024);
  gemm_f32<2><<<dim3(16, 16), blk, 0, stream>>>(enc, 1024, ckw, 1024, ckb, nullptr, 1.0f, ckf, 1024, 1024);
  gemm_f32<2><<<dim3(16, 16), blk, 0, stream>>>(enc, 1024, cvw, 1024, cvb, nullptr, 1.0f, cvf, 1024, 1024);
  attn_split<false><<<dim3(S_ / 64, B_ * NH_), blk, 0, stream>>>(
      cqf, ckf, cvf, cof, emask, flags, S_, SE_, 0.125f);
  gemm_f32<3><<<dim3(32, 16), blk, 0, stream>>>(cof, 1024, cow, 1024, cob, x1, 1.0f, x2, 1024, 1024);

  // ---- MoE block ----
  rmsnorm_kern<<<T_, blk, 0, stream>>>(x2, pln, h3b);
  hipMemsetAsync(meta, 0, 64, stream);   // counts + cursor
  router_kern<<<T_, dim3(64), 0, stream>>>(x2, pln, gatew, topi, topw, counts);
  finalize_kern<<<1, blk, 0, stream>>>(counts, poff, tm_e, tm_slot, ntl, perm);
  scatter_kern<<<(T_ + 255) / 256, blk, 0, stream>>>(topi, topw, poff, cursor, perm, pwgt);
  gemm_bt<4, true><<<dim3(MAXRT, FF_ / 64), blk, 0, stream>>>(
      h3b, 1024, w1, w3, 1024, (long)FF_ * H_,
      nullptr, ffh, FF_, tm_e, tm_slot, ntl, perm, pwgt, 1024);
  hipMemcpyAsync(out, x2, (size_t)T_ * H_ * 4, hipMemcpyDeviceToDevice, stream);
  gemm_bt<5, false><<<dim3(MAXRT, H_ / 64), blk, 0, stream>>>(
      ffh, FF_, w2, nullptr, FF_, (long)H_ * FF_,
      out, nullptr, 1024, tm_e, tm_slot, ntl, perm, pwgt, 2048);
}

// Round 4
// 710.993 us; speedup vs baseline: 1.1435x; 1.1435x over previous
//
#include <hip/hip_runtime.h>

// ---------------- problem constants ----------------
#define B_    2
#define S_    1024
#define H_    1024
#define NH_   16
#define HD_   64
#define SE_   512
#define E_    1024
#define NEXP_ 8
#define FF_   2048
#define T_    (B_*S_)    // 2048 tokens
#define TE_   (B_*SE_)   // 1024 encoder tokens
#define PERM_MAX 6400    // 128-padded slots: <= 4096 + 8*127
#define MAXRT 48         // max 128-row tiles

typedef short v8s __attribute__((ext_vector_type(8)));
typedef short v4s __attribute__((ext_vector_type(4)));
typedef float v4f __attribute__((ext_vector_type(4)));
typedef _Float16 v8h __attribute__((ext_vector_type(8)));

__device__ __forceinline__ unsigned short f2b(float f) {
  unsigned int u = __float_as_uint(f);
  u = (u + 0x7FFFu + ((u >> 16) & 1u)) >> 16;   // RNE f32 -> bf16 bits
  return (unsigned short)u;
}
__device__ __forceinline__ float b2f(unsigned short h) {
  return __uint_as_float(((unsigned int)h) << 16);
}

// async global->LDS, 16 bytes/lane; lds base must be wave-uniform
__device__ __forceinline__ void g2l16(const unsigned short* g, unsigned short* l) {
  __builtin_amdgcn_global_load_lds(
      (const __attribute__((address_space(1))) unsigned int*)g,
      (__attribute__((address_space(3))) unsigned int*)l, 16, 0, 0);
}

// ---------------- int64-vs-int32 ABI detect ----------------
__global__ void detect_kern(const int* __restrict__ pos, const int* __restrict__ msk,
                            int* __restrict__ flags) {
  if (threadIdx.x == 0) {
    flags[0] = (pos[1] == 1) ? 0 : 1;
    flags[1] = (msk[1] == 1) ? 0 : 1;
  }
}

// ---------------- RMSNorm f32 -> f32 ----------------
__global__ __launch_bounds__(256)
void rmsnorm_f32_kern(const float* __restrict__ x, const float* __restrict__ w,
                      float* __restrict__ y) {
  int row = blockIdx.x, tid = threadIdx.x;
  const float* xr = x + (long)row * 1024;
  v4f v = *(const v4f*)&xr[tid * 4];
  float ss = v[0]*v[0] + v[1]*v[1] + v[2]*v[2] + v[3]*v[3];
  #pragma unroll
  for (int off = 32; off; off >>= 1) ss += __shfl_xor(ss, off);
  __shared__ float sw[4];
  if ((tid & 63) == 0) sw[tid >> 6] = ss;
  __syncthreads();
  float tot = sw[0] + sw[1] + sw[2] + sw[3];
  float rs = rsqrtf(tot * (1.0f / 1024.0f) + 1e-6f);
  const float* wr = w + tid * 4;
  v4f o;
  #pragma unroll
  for (int j = 0; j < 4; ++j) o[j] = v[j] * rs * wr[j];
  *(v4f*)&y[(long)row * 1024 + tid * 4] = o;
}

// ---------------- RMSNorm f32 -> bf16 (MoE h3) ----------------
__global__ __launch_bounds__(256)
void rmsnorm_kern(const float* __restrict__ x, const float* __restrict__ w,
                  unsigned short* __restrict__ y) {
  int row = blockIdx.x, tid = threadIdx.x;
  const float* xr = x + (long)row * 1024;
  v4f v = *(const v4f*)&xr[tid * 4];
  float ss = v[0]*v[0] + v[1]*v[1] + v[2]*v[2] + v[3]*v[3];
  #pragma unroll
  for (int off = 32; off; off >>= 1) ss += __shfl_xor(ss, off);
  __shared__ float sw[4];
  if ((tid & 63) == 0) sw[tid >> 6] = ss;
  __syncthreads();
  float tot = sw[0] + sw[1] + sw[2] + sw[3];
  float rs = rsqrtf(tot * (1.0f / 1024.0f) + 1e-6f);
  const float* wr = w + tid * 4;
  v4s o;
  #pragma unroll
  for (int j = 0; j < 4; ++j) o[j] = (short)f2b(v[j] * rs * wr[j]);
  *(v4s*)&y[(long)row * 1024 + tid * 4] = o;
}

// ---------------- f32 -> bf16 convert (4 elems / thread) ----------------
__global__ __launch_bounds__(256)
void cvt_kern(const float* __restrict__ x, unsigned short* __restrict__ y, int n4) {
  int i = blockIdx.x * 256 + threadIdx.x;
  if (i >= n4) return;
  v4f v = *(const v4f*)&x[i * 4];
  v4s o;
  #pragma unroll
  for (int j = 0; j < 4; ++j) o[j] = (short)f2b(v[j]);
  *(v4s*)&y[i * 4] = o;
}

// ---------------- RoPE in-place on f32 q,k ----------------
__global__ __launch_bounds__(256)
void rope_f32_kern(float* __restrict__ q, float* __restrict__ k,
                   const int* __restrict__ pos, const int* __restrict__ flags) {
  int g = blockIdx.x * 256 + threadIdx.x;
  int d = g & 31;
  int h = (g >> 5) & 15;
  int s = (g >> 9) & (S_ - 1);
  int b = g >> 19;
  long base = (((long)(b * S_ + s)) * NH_ + h) * HD_;
  int pidx = b * S_ + s;
  int pv = pos[flags[0] ? (pidx << 1) : pidx];
  float p = (float)pv;
  float inv = powf(10000.0f, -(float)d * (1.0f / 32.0f));
  float f = p * inv;
  float sn = sinf(f), cs = cosf(f);
  float q1 = q[base + d], q2 = q[base + d + 32];
  q[base + d]      = q1 * cs - q2 * sn;
  q[base + d + 32] = q2 * cs + q1 * sn;
  float k1 = k[base + d], k2 = k[base + d + 32];
  k[base + d]      = k1 * cs - k2 * sn;
  k[base + d + 32] = k2 * cs + k1 * sn;
}

// ---------------- high-precision GEMM (split-fp16 3-pass) ----------------
// EPI: 0: C=acc | 2: C=(acc+bias)*scale | 3: C=resid+acc(+bias)
template<int EPI>
__global__ __launch_bounds__(256)
void gemm_f32(const float* __restrict__ A, int lda,
              const float* __restrict__ B, int ldb,
              const float* __restrict__ bias, const float* __restrict__ resid,
              float scale,
              float* __restrict__ Cf, int ldc, int K) {
  int row0 = blockIdx.x * 64, col0 = blockIdx.y * 64;
  int tid = threadIdx.x, lane = tid & 63, wid = tid >> 6;
  int wr = wid >> 1, wc = wid & 1;
  int lr = lane & 15, lg = lane >> 4;

  __shared__ _Float16 Ah[64][40], Al[64][40], Bh[64][40], Bl[64][40];

  v4f acc[2][2] = {};
  int ar = tid >> 2, ac = (tid & 3) * 8;
  const float* Ap = A + (long)(row0 + ar) * lda + ac;
  const float* Bp = B + (long)(col0 + ar) * ldb + ac;

  for (int k0 = 0; k0 < K; k0 += 32) {
    __syncthreads();
    v4f a0 = *(const v4f*)&Ap[k0];
    v4f a1 = *(const v4f*)&Ap[k0 + 4];
    v4f b0 = *(const v4f*)&Bp[k0];
    v4f b1 = *(const v4f*)&Bp[k0 + 4];
    v8h ahv, alv, bhv, blv;
    #pragma unroll
    for (int j = 0; j < 8; ++j) {
      float av = j < 4 ? a0[j] : a1[j - 4];
      _Float16 hh = (_Float16)av;
      ahv[j] = hh; alv[j] = (_Float16)(av - (float)hh);
      float bv = j < 4 ? b0[j] : b1[j - 4];
      hh = (_Float16)bv;
      bhv[j] = hh; blv[j] = (_Float16)(bv - (float)hh);
    }
    *(v8h*)&Ah[ar][ac] = ahv;
    *(v8h*)&Al[ar][ac] = alv;
    *(v8h*)&Bh[ar][ac] = bhv;
    *(v8h*)&Bl[ar][ac] = blv;
    __syncthreads();

    v8h ah[2], al2[2], bh[2], bl2[2];
    #pragma unroll
    for (int m = 0; m < 2; ++m) {
      ah[m]  = *(const v8h*)&Ah[wr*32 + m*16 + lr][lg*8];
      al2[m] = *(const v8h*)&Al[wr*32 + m*16 + lr][lg*8];
    }
    #pragma unroll
    for (int n = 0; n < 2; ++n) {
      bh[n]  = *(const v8h*)&Bh[wc*32 + n*16 + lr][lg*8];
      bl2[n] = *(const v8h*)&Bl[wc*32 + n*16 + lr][lg*8];
    }
    #pragma unroll
    for (int m = 0; m < 2; ++m)
      #pragma unroll
      for (int n = 0; n < 2; ++n) {
        acc[m][n] = __builtin_amdgcn_mfma_f32_16x16x32_f16(ah[m],  bh[n],  acc[m][n], 0, 0, 0);
        acc[m][n] = __builtin_amdgcn_mfma_f32_16x16x32_f16(ah[m],  bl2[n], acc[m][n], 0, 0, 0);
        acc[m][n] = __builtin_amdgcn_mfma_f32_16x16x32_f16(al2[m], bh[n],  acc[m][n], 0, 0, 0);
      }
  }

  #pragma unroll
  for (int m = 0; m < 2; ++m) {
    int rl = wr * 32 + m * 16 + lg * 4;
    #pragma unroll
    for (int n = 0; n < 2; ++n) {
      int gcol = col0 + wc * 32 + n * 16 + lr;
      #pragma unroll
      for (int rr = 0; rr < 4; ++rr) {
        int grow = row0 + rl + rr;
        float v = acc[m][n][rr];
        if constexpr (EPI == 0) {
          Cf[(long)grow * ldc + gcol] = v;
        } else if constexpr (EPI == 2) {
          Cf[(long)grow * ldc + gcol] = (v + bias[gcol]) * scale;
        } else if constexpr (EPI == 3) {
          float bb = bias ? bias[gcol] : 0.0f;
          Cf[(long)grow * ldc + gcol] = resid[(long)grow * ldc + gcol] + v + bb;
        }
      }
    }
  }
}

// ---------------- flash attention, split-fp16 3-pass, f32 in/out ----------
template<bool CAUSAL>
__global__ __launch_bounds__(256)
void attn_split(const float* __restrict__ Q, const float* __restrict__ Kp,
                const float* __restrict__ Vp, float* __restrict__ O,
                const int* __restrict__ mask, const int* __restrict__ flags,
                int Sq, int Sk, float qscale) {
  int qt = blockIdx.x, bh = blockIdx.y;
  int b = bh >> 4, h = bh & 15;
  int tid = threadIdx.x, lane = tid & 63, w = tid >> 6;
  int lr = lane & 15, lg = lane >> 4;
  int q0 = qt * 64;
  int mf = (!CAUSAL && mask) ? flags[1] : 0;

  __shared__ _Float16 Kh[64][72], Kl[64][72];
  __shared__ _Float16 Vh[64][72], Vl[64][72];     // transposed [d][key]
  __shared__ _Float16 Psh[4][16][72], Psl[4][16][72];

  v8h qh[2], ql[2];
  {
    long qbase = ((long)(b * Sq + q0 + w * 16 + lr) * NH_ + h) * HD_;
    #pragma unroll
    for (int kk = 0; kk < 2; ++kk) {
      v4f f0 = *(const v4f*)&Q[qbase + kk * 32 + lg * 8];
      v4f f1 = *(const v4f*)&Q[qbase + kk * 32 + lg * 8 + 4];
      #pragma unroll
      for (int j = 0; j < 8; ++j) {
        float f = (j < 4 ? f0[j] : f1[j - 4]) * qscale;
        _Float16 hh = (_Float16)f;
        qh[kk][j] = hh;
        ql[kk][j] = (_Float16)(f - (float)hh);
      }
    }
  }
  v4f of[4] = {};
  float m4[4], l4[4];
  #pragma unroll
  for (int i = 0; i < 4; ++i) { m4[i] = -3e38f; l4[i] = 0.0f; }

  int nkt = CAUSAL ? (qt + 1) : (Sk >> 6);
  for (int kt = 0; kt < nkt; ++kt) {
    __syncthreads();
    #pragma unroll
    for (int i = 0; i < 2; ++i) {
      int idx = tid + i * 256;
      int r = idx >> 3, c = (idx & 7) * 8;
      long gb = ((long)(b * Sk + kt * 64 + r) * NH_ + h) * HD_ + c;
      v4f k0v = *(const v4f*)&Kp[gb];
      v4f k1v = *(const v4f*)&Kp[gb + 4];
      v4f v0v = *(const v4f*)&Vp[gb];
      v4f v1v = *(const v4f*)&Vp[gb + 4];
      v8h khv, klv;
      #pragma unroll
      for (int j = 0; j < 8; ++j) {
        float kf = j < 4 ? k0v[j] : k1v[j - 4];
        _Float16 hh = (_Float16)kf;
        khv[j] = hh; klv[j] = (_Float16)(kf - (float)hh);
        float vf = j < 4 ? v0v[j] : v1v[j - 4];
        hh = (_Float16)vf;
        Vh[c + j][r] = hh; Vl[c + j][r] = (_Float16)(vf - (float)hh);
      }
      *(v8h*)&Kh[r][c] = khv;
      *(v8h*)&Kl[r][c] = klv;
    }
    __syncthreads();

    v4f sf[4] = {};
    #pragma unroll
    for (int kk = 0; kk < 2; ++kk)
      #pragma unroll
      for (int n = 0; n < 4; ++n) {
        v8h kbh = *(const v8h*)&Kh[n * 16 + lr][kk * 32 + lg * 8];
        v8h kbl = *(const v8h*)&Kl[n * 16 + lr][kk * 32 + lg * 8];
        sf[n] = __builtin_amdgcn_mfma_f32_16x16x32_f16(qh[kk], kbh, sf[n], 0, 0, 0);
        sf[n] = __builtin_amdgcn_mfma_f32_16x16x32_f16(qh[kk], kbl, sf[n], 0, 0, 0);
        sf[n] = __builtin_amdgcn_mfma_f32_16x16x32_f16(ql[kk], kbh, sf[n], 0, 0, 0);
      }

    if constexpr (CAUSAL) {
      if (kt == qt) {
        #pragma unroll
        for (int n = 0; n < 4; ++n) {
          int kcol = kt * 64 + n * 16 + lr;
          #pragma unroll
          for (int rr = 0; rr < 4; ++rr) {
            int qr = q0 + w * 16 + lg * 4 + rr;
            if (kcol > qr) sf[n][rr] = -1e9f;
          }
        }
      }
    } else {
      if (mask) {
        #pragma unroll
        for (int n = 0; n < 4; ++n) {
          int kcol = kt * 64 + n * 16 + lr;
          int mi = b * Sk + kcol;
          if (mask[mf ? (mi << 1) : mi] == 0) {
            #pragma unroll
            for (int rr = 0; rr < 4; ++rr) sf[n][rr] = -1e9f;
          }
        }
      }
    }

    float al[4];
    #pragma unroll
    for (int rr = 0; rr < 4; ++rr) {
      float mx = fmaxf(fmaxf(sf[0][rr], sf[1][rr]), fmaxf(sf[2][rr], sf[3][rr]));
      #pragma unroll
      for (int off = 8; off; off >>= 1) mx = fmaxf(mx, __shfl_xor(mx, off));
      float mn = fmaxf(m4[rr], mx);
      al[rr] = __expf(m4[rr] - mn);
      m4[rr] = mn;
      float rs = 0.0f;
      #pragma unroll
      for (int n = 0; n < 4; ++n) {
        float pv = __expf(sf[n][rr] - mn);
        sf[n][rr] = pv;
        rs += pv;
      }
      #pragma unroll
      for (int off = 8; off; off >>= 1) rs += __shfl_xor(rs, off);
      l4[rr] = l4[rr] * al[rr] + rs;
    }

    #pragma unroll
    for (int n = 0; n < 4; ++n)
      #pragma unroll
      for (int rr = 0; rr < 4; ++rr) {
        of[n][rr] *= al[rr];
        float pv = sf[n][rr];
        _Float16 ph = (_Float16)pv;
        Psh[w][lg * 4 + rr][n * 16 + lr] = ph;
        Psl[w][lg * 4 + rr][n * 16 + lr] = (_Float16)(pv - (float)ph);
      }
    __syncthreads();

    #pragma unroll
    for (int kc = 0; kc < 2; ++kc) {
      v8h pah = *(const v8h*)&Psh[w][lr][kc * 32 + lg * 8];
      v8h pal = *(const v8h*)&Psl[w][lr][kc * 32 + lg * 8];
      #pragma unroll
      for (int n = 0; n < 4; ++n) {
        v8h vbh = *(const v8h*)&Vh[n * 16 + lr][kc * 32 + lg * 8];
        v8h vbl = *(const v8h*)&Vl[n * 16 + lr][kc * 32 + lg * 8];
        of[n] = __builtin_amdgcn_mfma_f32_16x16x32_f16(pah, vbh, of[n], 0, 0, 0);
        of[n] = __builtin_amdgcn_mfma_f32_16x16x32_f16(pah, vbl, of[n], 0, 0, 0);
        of[n] = __builtin_amdgcn_mfma_f32_16x16x32_f16(pal, vbh, of[n], 0, 0, 0);
      }
    }
  }

  #pragma unroll
  for (int rr = 0; rr < 4; ++rr) {
    int qr = q0 + w * 16 + lg * 4 + rr;
    float inv = 1.0f / l4[rr];
    long ob = (long)(b * Sq + qr) * 1024 + h * 64;
    #pragma unroll
    for (int n = 0; n < 4; ++n) O[ob + n * 16 + lr] = of[n][rr] * inv;
  }
}

// ---------------- MoE GEMM1: 128x64 tile, dual-B swiglu, bf16 weights -------
// C[slot, col] = silu(A@B1^T) * (A@B2^T); A gathered via perm (clamped).
__global__ __launch_bounds__(256)
void moe_gemm1(const unsigned short* __restrict__ A,              // h3b [T,1024]
               const unsigned short* __restrict__ B1,             // w1b [e,2048,1024]
               const unsigned short* __restrict__ B2,             // w3b
               unsigned short* __restrict__ Cb,                   // ffh [slots,2048]
               const int* __restrict__ tm_e, const int* __restrict__ tm_slot,
               const int* __restrict__ ntl, const int* __restrict__ perm) {
  int tile = blockIdx.x;
  if (tile >= ntl[0]) return;
  int e = tm_e[tile];
  int row0 = tm_slot[tile];
  const unsigned short* Bp1 = B1 + (long)e * (FF_ * H_);
  const unsigned short* Bp2 = B2 + (long)e * (FF_ * H_);
  int col0 = blockIdx.y * 64;
  int tid = threadIdx.x, lane = tid & 63, w = tid >> 6;
  int lr = lane & 15, lg = lane >> 4;
  int wr = w >> 1, wc = w & 1;

  __shared__ unsigned short As[128 * 32];
  __shared__ unsigned short Bs1[64 * 32];
  __shared__ unsigned short Bs2[64 * 32];

  // global staging srcs: A chunks c = i*256+tid (i=0,1), B chunks c = tid
  const unsigned short* ga[2];
  #pragma unroll
  for (int i = 0; i < 2; ++i) {
    int c = i * 256 + tid;
    int r = c >> 2, sub = c & 3;
    int tok = perm[row0 + r];
    ga[i] = A + (long)(tok < 0 ? 0 : tok) * H_ + sub * 8;
  }
  int rb = tid >> 2, subb = (tid & 3) * 8;
  const unsigned short* gb1 = Bp1 + (long)(col0 + rb) * H_ + subb;
  const unsigned short* gb2 = Bp2 + (long)(col0 + rb) * H_ + subb;

  v4f acc[4][2] = {};
  v4f acc2[4][2] = {};

  for (int k0 = 0; k0 < H_; k0 += 32) {
    __syncthreads();
    #pragma unroll
    for (int i = 0; i < 2; ++i)
      g2l16(ga[i] + k0, As + (size_t)(i * 256 + w * 64) * 8);
    g2l16(gb1 + k0, Bs1 + (size_t)(w * 64) * 8);
    g2l16(gb2 + k0, Bs2 + (size_t)(w * 64) * 8);
    __syncthreads();

    v8s a[4], b[2];
    #pragma unroll
    for (int m = 0; m < 4; ++m) a[m] = *(const v8s*)&As[(wr * 64 + m * 16 + lr) * 32 + lg * 8];
    #pragma unroll
    for (int n = 0; n < 2; ++n) b[n] = *(const v8s*)&Bs1[(wc * 32 + n * 16 + lr) * 32 + lg * 8];
    #pragma unroll
    for (int m = 0; m < 4; ++m)
      #pragma unroll
      for (int n = 0; n < 2; ++n)
        acc[m][n] = __builtin_amdgcn_mfma_f32_16x16x32_bf16(a[m], b[n], acc[m][n], 0, 0, 0);
    #pragma unroll
    for (int n = 0; n < 2; ++n) b[n] = *(const v8s*)&Bs2[(wc * 32 + n * 16 + lr) * 32 + lg * 8];
    #pragma unroll
    for (int m = 0; m < 4; ++m)
      #pragma unroll
      for (int n = 0; n < 2; ++n)
        acc2[m][n] = __builtin_amdgcn_mfma_f32_16x16x32_bf16(a[m], b[n], acc2[m][n], 0, 0, 0);
  }

  #pragma unroll
  for (int m = 0; m < 4; ++m) {
    int grow = row0 + wr * 64 + m * 16 + lg * 4;
    #pragma unroll
    for (int n = 0; n < 2; ++n) {
      int gcol = col0 + wc * 32 + n * 16 + lr;
      #pragma unroll
      for (int rr = 0; rr < 4; ++rr) {
        float v = acc[m][n][rr];
        float g = v / (1.0f + __expf(-v));
        Cb[(long)(grow + rr) * FF_ + gcol] = f2b(g * acc2[m][n][rr]);
      }
    }
  }
}

// ---------------- MoE GEMM2: 128x128 tile, scatter-accumulate ----------------
__global__ __launch_bounds__(256)
void moe_gemm2(const unsigned short* __restrict__ A,              // ffh [slots,2048]
               const unsigned short* __restrict__ B,              // w2b [e,1024,2048]
               float* __restrict__ Cf,                            // out [T,1024]
               const int* __restrict__ tm_e, const int* __restrict__ tm_slot,
               const int* __restrict__ ntl,
               const int* __restrict__ perm, const float* __restrict__ pwgt) {
  int tile = blockIdx.x;
  if (tile >= ntl[0]) return;
  int e = tm_e[tile];
  int row0 = tm_slot[tile];
  const unsigned short* Bp = B + (long)e * (H_ * FF_);
  int col0 = blockIdx.y * 128;
  int tid = threadIdx.x, lane = tid & 63, w = tid >> 6;
  int lr = lane & 15, lg = lane >> 4;
  int wr = w >> 1, wc = w & 1;

  __shared__ unsigned short As[128 * 32];
  __shared__ unsigned short Bs[128 * 32];

  const unsigned short* ga[2];
  const unsigned short* gb[2];
  #pragma unroll
  for (int i = 0; i < 2; ++i) {
    int c = i * 256 + tid;
    int r = c >> 2, sub = c & 3;
    ga[i] = A + (long)(row0 + r) * FF_ + sub * 8;
    gb[i] = Bp + (long)(col0 + r) * FF_ + sub * 8;
  }

  v4f acc[4][4] = {};

  for (int k0 = 0; k0 < FF_; k0 += 32) {
    __syncthreads();
    #pragma unroll
    for (int i = 0; i < 2; ++i) {
      g2l16(ga[i] + k0, As + (size_t)(i * 256 + w * 64) * 8);
      g2l16(gb[i] + k0, Bs + (size_t)(i * 256 + w * 64) * 8);
    }
    __syncthreads();

    v8s a[4], b[4];
    #pragma unroll
    for (int m = 0; m < 4; ++m) a[m] = *(const v8s*)&As[(wr * 64 + m * 16 + lr) * 32 + lg * 8];
    #pragma unroll
    for (int n = 0; n < 4; ++n) b[n] = *(const v8s*)&Bs[(wc * 64 + n * 16 + lr) * 32 + lg * 8];
    #pragma unroll
    for (int m = 0; m < 4; ++m)
      #pragma unroll
      for (int n = 0; n < 4; ++n)
        acc[m][n] = __builtin_amdgcn_mfma_f32_16x16x32_bf16(a[m], b[n], acc[m][n], 0, 0, 0);
  }

  #pragma unroll
  for (int m = 0; m < 4; ++m) {
    int grow = row0 + wr * 64 + m * 16 + lg * 4;
    #pragma unroll
    for (int rr = 0; rr < 4; ++rr) {
      int tok = perm[grow + rr];
      if (tok < 0) continue;
      float pw = pwgt[grow + rr];
      #pragma unroll
      for (int n = 0; n < 4; ++n) {
        int gcol = col0 + wc * 64 + n * 16 + lr;
        atomicAdd(&Cf[(long)tok * H_ + gcol], acc[m][n][rr] * pw);
      }
    }
  }
}

// ---------------- MoE router: f32 rms + logits + top-2 ----------------
__global__ __launch_bounds__(64)
void router_kern(const float* __restrict__ x, const float* __restrict__ w,
                 const float* __restrict__ gw,
                 int* __restrict__ topi, float* __restrict__ topw,
                 int* __restrict__ counts) {
  int t = blockIdx.x, lane = threadIdx.x;
  const float* xr = x + (long)t * 1024;
  float vals[16];
  float ss = 0.0f;
  #pragma unroll
  for (int i = 0; i < 16; ++i) { float v = xr[lane + i * 64]; vals[i] = v; ss += v * v; }
  #pragma unroll
  for (int off = 32; off; off >>= 1) ss += __shfl_xor(ss, off);
  float rs = rsqrtf(ss * (1.0f / 1024.0f) + 1e-6f);
  #pragma unroll
  for (int i = 0; i < 16; ++i) vals[i] *= rs * w[lane + i * 64];
  float lgts[8];
  #pragma unroll
  for (int e = 0; e < 8; ++e) {
    const float* g = gw + e * 1024;
    float s = 0.0f;
    #pragma unroll
    for (int i = 0; i < 16; ++i) s += vals[i] * g[lane + i * 64];
    #pragma unroll
    for (int off = 32; off; off >>= 1) s += __shfl_xor(s, off);
    lgts[e] = s;
  }
  int i1 = 0; float l1 = lgts[0];
  #pragma unroll
  for (int e = 1; e < 8; ++e) if (lgts[e] > l1) { l1 = lgts[e]; i1 = e; }
  int i2 = -1; float l2 = -3e38f;
  #pragma unroll
  for (int e = 0; e < 8; ++e) if (e != i1 && lgts[e] > l2) { l2 = lgts[e]; i2 = e; }
  float w1 = 1.0f / (1.0f + __expf(l2 - l1));
  if (lane == 0) {
    topi[t * 2] = i1; topi[t * 2 + 1] = i2;
    topw[t * 2] = w1; topw[t * 2 + 1] = 1.0f - w1;
    atomicAdd(&counts[i1], 1);
    atomicAdd(&counts[i2], 1);
  }
}

// ---------------- MoE finalize: 128-padded offsets + tile map ----------------
__global__ __launch_bounds__(256)
void finalize_kern(const int* __restrict__ counts, int* __restrict__ poff,
                   int* __restrict__ tm_e, int* __restrict__ tm_slot,
                   int* __restrict__ ntl, int* __restrict__ perm) {
  __shared__ int stot;
  if (threadIdx.x == 0) {
    int off = 0, nt = 0;
    for (int e = 0; e < 8; ++e) {
      poff[e] = off;
      int c = counts[e];
      int ntE = (c + 127) >> 7;
      for (int i = 0; i < ntE; ++i) { tm_e[nt] = e; tm_slot[nt] = off + i * 128; ++nt; }
      off += ntE * 128;
    }
    ntl[0] = nt; ntl[1] = off;
    stot = off;
  }
  __syncthreads();
  for (int s = threadIdx.x; s < stot; s += 256) perm[s] = -1;
}

__global__ __launch_bounds__(256)
void scatter_kern(const int* __restrict__ topi, const float* __restrict__ topw,
                  const int* __restrict__ poff, int* __restrict__ cursor,
                  int* __restrict__ perm, float* __restrict__ pwgt) {
  int t = blockIdx.x * 256 + threadIdx.x;
  if (t >= T_) return;
  #pragma unroll
  for (int kk = 0; kk < 2; ++kk) {
    int e = topi[t * 2 + kk];
    int pos = atomicAdd(&cursor[e], 1);
    int slot = poff[e] + pos;
    perm[slot] = t;
    pwgt[slot] = topw[t * 2 + kk];
  }
}

// ---------------- host launcher ----------------
extern "C" void kernel_launch(void* const* d_in, const int* in_sizes, int n_in,
                              void* d_out, int out_size, void* d_ws, size_t ws_size,
                              hipStream_t stream) {
  (void)in_sizes; (void)n_in; (void)out_size; (void)ws_size;
  const float* x_in  = (const float*)d_in[0];
  const int*  posids = (const int*)d_in[1];
  const float* enc   = (const float*)d_in[2];
  const int*  emask  = (const int*)d_in[3];
  const float* inln  = (const float*)d_in[4];
  const float* wq    = (const float*)d_in[5];
  const float* wk    = (const float*)d_in[6];
  const float* wv    = (const float*)d_in[7];
  const float* wo    = (const float*)d_in[8];
  const float* cnorm = (const float*)d_in[9];
  const float* cqw   = (const float*)d_in[10];
  const float* cqb   = (const float*)d_in[11];
  const float* ckw   = (const float*)d_in[12];
  const float* ckb   = (const float*)d_in[13];
  const float* cvw   = (const float*)d_in[14];
  const float* cvb   = (const float*)d_in[15];
  const float* cow   = (const float*)d_in[16];
  const float* cob   = (const float*)d_in[17];
  const float* pln   = (const float*)d_in[18];
  const float* gatew = (const float*)d_in[19];
  const float* w1    = (const float*)d_in[20];
  const float* w2    = (const float*)d_in[21];
  const float* w3    = (const float*)d_in[22];
  float* out = (float*)d_out;

  char* p = (char*)d_ws;
  auto alloc = [&](size_t bytes) -> char* {
    char* r = p;
    p += (bytes + 255) & ~(size_t)255;
    return r;
  };
  float* h    = (float*)alloc((size_t)T_ * H_ * 4);
  float* qf   = (float*)alloc((size_t)T_ * H_ * 4);
  float* kf   = (float*)alloc((size_t)T_ * H_ * 4);
  float* vf   = (float*)alloc((size_t)T_ * H_ * 4);
  float* of   = (float*)alloc((size_t)T_ * H_ * 4);
  float* x1   = (float*)alloc((size_t)T_ * H_ * 4);
  float* h2   = (float*)alloc((size_t)T_ * H_ * 4);
  float* x2   = (float*)alloc((size_t)T_ * H_ * 4);
  unsigned short* h3b = (unsigned short*)alloc((size_t)T_ * H_ * 2);
  int*   meta    = (int*)alloc(4 * (8 + 8 + 8 + 2 + 2 + MAXRT + MAXRT));
  int*   counts  = meta;
  int*   cursor  = meta + 8;
  int*   poff    = meta + 16;
  int*   ntl     = meta + 24;
  int*   flags   = meta + 26;
  int*   tm_e    = meta + 28;
  int*   tm_slot = meta + 28 + MAXRT;
  int*   topi    = (int*)alloc((size_t)T_ * 2 * 4);
  float* topw    = (float*)alloc((size_t)T_ * 2 * 4);
  int*   perm    = (int*)alloc((size_t)PERM_MAX * 4);
  float* pwgt    = (float*)alloc((size_t)PERM_MAX * 4);
  unsigned short* w1b = (unsigned short*)alloc((size_t)NEXP_ * FF_ * H_ * 2);
  unsigned short* w3b = (unsigned short*)alloc((size_t)NEXP_ * FF_ * H_ * 2);
  unsigned short* w2b = (unsigned short*)alloc((size_t)NEXP_ * H_ * FF_ * 2);
  // ffh aliased onto dead f32 region (h..h2: used only pre-MoE; 26 MB < 58 MB)
  unsigned short* ffh = (unsigned short*)h;

  // cross-attn aliases (qf/kf/vf/of dead after self-attn)
  float* cqf = qf;
  float* ckf = kf;
  float* cvf = vf;
  float* cof = of;

  dim3 blk(256);

  detect_kern<<<1, 64, 0, stream>>>(posids, emask, flags);

  // weight pre-convert to bf16 (MoE)
  cvt_kern<<<(NEXP_ * FF_ * H_ / 4 + 255) / 256, blk, 0, stream>>>(w1, w1b, NEXP_ * FF_ * H_ / 4);
  cvt_kern<<<(NEXP_ * FF_ * H_ / 4 + 255) / 256, blk, 0, stream>>>(w3, w3b, NEXP_ * FF_ * H_ / 4);
  cvt_kern<<<(NEXP_ * H_ * FF_ / 4 + 255) / 256, blk, 0, stream>>>(w2, w2b, NEXP_ * H_ * FF_ / 4);

  // ---- self-attention block ----
  rmsnorm_f32_kern<<<T_, blk, 0, stream>>>(x_in, inln, h);
  gemm_f32<0><<<dim3(32, 16), blk, 0, stream>>>(h, 1024, wq, 1024, nullptr, nullptr, 1.0f, qf, 1024, 1024);
  gemm_f32<0><<<dim3(32, 16), blk, 0, stream>>>(h, 1024, wk, 1024, nullptr, nullptr, 1.0f, kf, 1024, 1024);
  gemm_f32<0><<<dim3(32, 16), blk, 0, stream>>>(h, 1024, wv, 1024, nullptr, nullptr, 1.0f, vf, 1024, 1024);
  rope_f32_kern<<<(B_ * S_ * NH_ * 32) / 256, blk, 0, stream>>>(qf, kf, posids, flags);
  attn_split<true><<<dim3(S_ / 64, B_ * NH_), blk, 0, stream>>>(
      qf, kf, vf, of, nullptr, flags, S_, S_, 0.125f);
  gemm_f32<3><<<dim3(32, 16), blk, 0, stream>>>(of, 1024, wo, 1024, nullptr, x_in, 1.0f, x1, 1024, 1024);

  // ---- cross-attention block ----
  rmsnorm_f32_kern<<<T_, blk, 0, stream>>>(x1, cnorm, h2);
  gemm_f32<2><<<dim3(32, 16), blk, 0, stream>>>(h2, 1024, cqw, 1024, cqb, nullptr, 1.0f, cqf, 1024, 1024);
  gemm_f32<2><<<dim3(16, 16), blk, 0, stream>>>(enc, 1024, ckw, 1024, ckb, nullptr, 1.0f, ckf, 1024, 1024);
  gemm_f32<2><<<dim3(16, 16), blk, 0, stream>>>(enc, 1024, cvw, 1024, cvb, nullptr, 1.0f, cvf, 1024, 1024);
  attn_split<false><<<dim3(S_ / 64, B_ * NH_), blk, 0, stream>>>(
      cqf, ckf, cvf, cof, emask, flags, S_, SE_, 0.125f);
  gemm_f32<3><<<dim3(32, 16), blk, 0, stream>>>(cof, 1024, cow, 1024, cob, x1, 1.0f, x2, 1024, 1024);

  // ---- MoE block ----
  rmsnorm_kern<<<T_, blk, 0, stream>>>(x2, pln, h3b);
  hipMemsetAsync(meta, 0, 64, stream);   // counts + cursor
  router_kern<<<T_, dim3(64), 0, stream>>>(x2, pln, gatew, topi, topw, counts);
  finalize_kern<<<1, blk, 0, stream>>>(counts, poff, tm_e, tm_slot, ntl, perm);
  scatter_kern<<<(T_ + 255) / 256, blk, 0, stream>>>(topi, topw, poff, cursor, perm, pwgt);
  moe_gemm1<<<dim3(MAXRT, FF_ / 64), blk, 0, stream>>>(
      h3b, w1b, w3b, ffh, tm_e, tm_slot, ntl, perm);
  hipMemcpyAsync(out, x2, (size_t)T_ * H_ * 4, hipMemcpyDeviceToDevice, stream);
  moe_gemm2<<<dim3(MAXRT, H_ / 128), blk, 0, stream>>>(
      ffh, w2b, out, tm_e, tm_slot, ntl, perm, pwgt);
}

// Round 5
// 590.784 us; speedup vs baseline: 1.3761x; 1.2035x over previous
//
#include <hip/hip_runtime.h>

// ---------------- problem constants ----------------
#define B_    2
#define S_    1024
#define H_    1024
#define NH_   16
#define HD_   64
#define SE_   512
#define E_    1024
#define NEXP_ 8
#define FF_   2048
#define T_    (B_*S_)    // 2048 tokens
#define TE_   (B_*SE_)   // 1024 encoder tokens
#define PERM_MAX 6400
#define MAXRT 48

typedef short v8s __attribute__((ext_vector_type(8)));
typedef short v4s __attribute__((ext_vector_type(4)));
typedef float v4f __attribute__((ext_vector_type(4)));
typedef _Float16 v8h __attribute__((ext_vector_type(8)));
typedef _Float16 v4h __attribute__((ext_vector_type(4)));

__device__ __forceinline__ unsigned short f2b(float f) {
  unsigned int u = __float_as_uint(f);
  u = (u + 0x7FFFu + ((u >> 16) & 1u)) >> 16;   // RNE f32 -> bf16 bits
  return (unsigned short)u;
}
__device__ __forceinline__ float b2f(unsigned short h) {
  return __uint_as_float(((unsigned int)h) << 16);
}

// async global->LDS, 16 bytes/lane; lds base wave-uniform, global per-lane
__device__ __forceinline__ void g2l16(const void* g, void* l) {
  __builtin_amdgcn_global_load_lds(
      (const __attribute__((address_space(1))) unsigned int*)g,
      (__attribute__((address_space(3))) unsigned int*)l, 16, 0, 0);
}

// ---------------- int64-vs-int32 ABI detect ----------------
__global__ void detect_kern(const int* __restrict__ pos, const int* __restrict__ msk,
                            int* __restrict__ flags) {
  if (threadIdx.x == 0) {
    flags[0] = (pos[1] == 1) ? 0 : 1;
    flags[1] = (msk[1] == 1) ? 0 : 1;
  }
}

// ---------------- f32 -> fp16 hi/lo split (8 elems/thread) ----------------
__global__ __launch_bounds__(256)
void split_kern(const float* __restrict__ x, _Float16* __restrict__ oh,
                _Float16* __restrict__ ol, int n8) {
  int i = blockIdx.x * 256 + threadIdx.x;
  if (i >= n8) return;
  v4f a = *(const v4f*)&x[i * 8];
  v4f b = *(const v4f*)&x[i * 8 + 4];
  v8h hv, lv;
  #pragma unroll
  for (int j = 0; j < 8; ++j) {
    float v = j < 4 ? a[j] : b[j - 4];
    _Float16 hh = (_Float16)v;
    hv[j] = hh; lv[j] = (_Float16)(v - (float)hh);
  }
  *(v8h*)&oh[i * 8] = hv;
  *(v8h*)&ol[i * 8] = lv;
}

// ---------------- RMSNorm f32 -> fp16 hi/lo ----------------
__global__ __launch_bounds__(256)
void rmsnorm_hl_kern(const float* __restrict__ x, const float* __restrict__ w,
                     _Float16* __restrict__ yh, _Float16* __restrict__ yl) {
  int row = blockIdx.x, tid = threadIdx.x;
  const float* xr = x + (long)row * 1024;
  v4f v = *(const v4f*)&xr[tid * 4];
  float ss = v[0]*v[0] + v[1]*v[1] + v[2]*v[2] + v[3]*v[3];
  #pragma unroll
  for (int off = 32; off; off >>= 1) ss += __shfl_xor(ss, off);
  __shared__ float sw[4];
  if ((tid & 63) == 0) sw[tid >> 6] = ss;
  __syncthreads();
  float tot = sw[0] + sw[1] + sw[2] + sw[3];
  float rs = rsqrtf(tot * (1.0f / 1024.0f) + 1e-6f);
  const float* wr = w + tid * 4;
  v4h oh, ol;
  #pragma unroll
  for (int j = 0; j < 4; ++j) {
    float f = v[j] * rs * wr[j];
    _Float16 hh = (_Float16)f;
    oh[j] = hh; ol[j] = (_Float16)(f - (float)hh);
  }
  *(v4h*)&yh[(long)row * 1024 + tid * 4] = oh;
  *(v4h*)&yl[(long)row * 1024 + tid * 4] = ol;
}

// ---------------- RMSNorm f32 -> bf16 (MoE h3) ----------------
__global__ __launch_bounds__(256)
void rmsnorm_kern(const float* __restrict__ x, const float* __restrict__ w,
                  unsigned short* __restrict__ y) {
  int row = blockIdx.x, tid = threadIdx.x;
  const float* xr = x + (long)row * 1024;
  v4f v = *(const v4f*)&xr[tid * 4];
  float ss = v[0]*v[0] + v[1]*v[1] + v[2]*v[2] + v[3]*v[3];
  #pragma unroll
  for (int off = 32; off; off >>= 1) ss += __shfl_xor(ss, off);
  __shared__ float sw[4];
  if ((tid & 63) == 0) sw[tid >> 6] = ss;
  __syncthreads();
  float tot = sw[0] + sw[1] + sw[2] + sw[3];
  float rs = rsqrtf(tot * (1.0f / 1024.0f) + 1e-6f);
  const float* wr = w + tid * 4;
  v4s o;
  #pragma unroll
  for (int j = 0; j < 4; ++j) o[j] = (short)f2b(v[j] * rs * wr[j]);
  *(v4s*)&y[(long)row * 1024 + tid * 4] = o;
}

// ---------------- f32 -> bf16 convert (MoE weights) ----------------
__global__ __launch_bounds__(256)
void cvt_kern(const float* __restrict__ x, unsigned short* __restrict__ y, int n4) {
  int i = blockIdx.x * 256 + threadIdx.x;
  if (i >= n4) return;
  v4f v = *(const v4f*)&x[i * 4];
  v4s o;
  #pragma unroll
  for (int j = 0; j < 4; ++j) o[j] = (short)f2b(v[j]);
  *(v4s*)&y[i * 4] = o;
}

// ---------------- RoPE: q f32 in-place; k rotated -> fp16 hi/lo ----------
__global__ __launch_bounds__(256)
void rope_split_kern(float* __restrict__ q, const float* __restrict__ k,
                     _Float16* __restrict__ kh, _Float16* __restrict__ kl,
                     const int* __restrict__ pos, const int* __restrict__ flags) {
  int g = blockIdx.x * 256 + threadIdx.x;
  int d = g & 31;
  int h = (g >> 5) & 15;
  int s = (g >> 9) & (S_ - 1);
  int b = g >> 19;
  long base = (((long)(b * S_ + s)) * NH_ + h) * HD_;
  int pidx = b * S_ + s;
  int pv = pos[flags[0] ? (pidx << 1) : pidx];
  float p = (float)pv;
  float inv = powf(10000.0f, -(float)d * (1.0f / 32.0f));
  float f = p * inv;
  float sn = sinf(f), cs = cosf(f);
  float q1 = q[base + d], q2 = q[base + d + 32];
  q[base + d]      = q1 * cs - q2 * sn;
  q[base + d + 32] = q2 * cs + q1 * sn;
  float k1 = k[base + d], k2 = k[base + d + 32];
  float kr1 = k1 * cs - k2 * sn;
  float kr2 = k2 * cs + k1 * sn;
  _Float16 hh = (_Float16)kr1;
  kh[base + d] = hh; kl[base + d] = (_Float16)(kr1 - (float)hh);
  hh = (_Float16)kr2;
  kh[base + d + 32] = hh; kl[base + d + 32] = (_Float16)(kr2 - (float)hh);
}

// ---------------- V transpose + split: [B,Sk,NH,64]f32 -> [B,NH,64,Sk]f16 x2
__global__ __launch_bounds__(256)
void vtrans_kern(const float* __restrict__ vf, _Float16* __restrict__ vth,
                 _Float16* __restrict__ vtl, int Sk) {
  int kb = blockIdx.x, bh = blockIdx.y;
  int b = bh >> 4, h = bh & 15;
  int t = threadIdx.x;
  __shared__ float tile[64][65];
  int key = t >> 2, dsub = (t & 3) * 16;
  const float* src = vf + (((long)(b * Sk + kb * 64 + key)) * NH_ + h) * HD_ + dsub;
  #pragma unroll
  for (int j = 0; j < 16; j += 4) *(v4f*)&tile[key][dsub + j] = *(const v4f*)&src[j];
  __syncthreads();
  int d = t >> 2, ksub = (t & 3) * 16;
  v8h hv0, lv0, hv1, lv1;
  #pragma unroll
  for (int j = 0; j < 16; ++j) {
    float v = tile[ksub + j][d];
    _Float16 hh = (_Float16)v;
    if (j < 8) { hv0[j] = hh; lv0[j] = (_Float16)(v - (float)hh); }
    else       { hv1[j - 8] = hh; lv1[j - 8] = (_Float16)(v - (float)hh); }
  }
  long ob = (((long)(b * NH_ + h)) * HD_ + d) * Sk + kb * 64 + ksub;
  *(v8h*)&vth[ob] = hv0; *(v8h*)&vth[ob + 8] = hv1;
  *(v8h*)&vtl[ob] = lv0; *(v8h*)&vtl[ob + 8] = lv1;
}

// ---------------- split-fp16 3-pass GEMM, 128x64 tile, gload_lds staging ----
struct ZArg {
  const _Float16 *Ah, *Al, *Bh, *Bl;
  const float *bias, *resid;
  float *Cf;
  _Float16 *Ch, *Cl;
  int M;
};

__global__ __launch_bounds__(256)
void gemm_hl(ZArg z0, ZArg z1, ZArg z2, int K) {
  ZArg za = blockIdx.z == 0 ? z0 : (blockIdx.z == 1 ? z1 : z2);
  int row0 = blockIdx.x * 128;
  if (row0 >= za.M) return;
  int col0 = blockIdx.y * 64;
  int tid = threadIdx.x, lane = tid & 63, w = tid >> 6;
  int lr = lane & 15, lg = lane >> 4;
  int wr = w >> 1, wc = w & 1;

  __shared__ _Float16 Ah_s[128 * 32], Al_s[128 * 32];
  __shared__ _Float16 Bh_s[64 * 32], Bl_s[64 * 32];

  // staging coords
  int av0 = w * 64 + lane, av1 = (w + 4) * 64 + lane;
  int ar0 = av0 >> 2, as0 = av0 & 3;
  int ar1 = av1 >> 2, as1 = av1 & 3;
  int bv = w * 64 + lane;
  int br = bv >> 2, bs = bv & 3;
  const _Float16* ga0h = za.Ah + (long)(row0 + ar0) * K + as0 * 8;
  const _Float16* ga0l = za.Al + (long)(row0 + ar0) * K + as0 * 8;
  const _Float16* ga1h = za.Ah + (long)(row0 + ar1) * K + as1 * 8;
  const _Float16* ga1l = za.Al + (long)(row0 + ar1) * K + as1 * 8;
  const _Float16* gbh  = za.Bh + (long)(col0 + br) * K + bs * 8;
  const _Float16* gbl  = za.Bl + (long)(col0 + br) * K + bs * 8;

  v4f acc[4][2] = {};

  for (int k0 = 0; k0 < K; k0 += 32) {
    __syncthreads();
    g2l16(ga0h + k0, (char*)Ah_s + w * 1024);
    g2l16(ga1h + k0, (char*)Ah_s + (w + 4) * 1024);
    g2l16(ga0l + k0, (char*)Al_s + w * 1024);
    g2l16(ga1l + k0, (char*)Al_s + (w + 4) * 1024);
    g2l16(gbh + k0, (char*)Bh_s + w * 1024);
    g2l16(gbl + k0, (char*)Bl_s + w * 1024);
    __syncthreads();

    v8h ah[4], al[4], bh[2], bl[2];
    #pragma unroll
    for (int m = 0; m < 4; ++m) {
      int off = (wr * 64 + m * 16 + lr) * 64 + lg * 16;
      ah[m] = *(const v8h*)((char*)Ah_s + off);
      al[m] = *(const v8h*)((char*)Al_s + off);
    }
    #pragma unroll
    for (int n = 0; n < 2; ++n) {
      int off = (wc * 32 + n * 16 + lr) * 64 + lg * 16;
      bh[n] = *(const v8h*)((char*)Bh_s + off);
      bl[n] = *(const v8h*)((char*)Bl_s + off);
    }
    #pragma unroll
    for (int m = 0; m < 4; ++m)
      #pragma unroll
      for (int n = 0; n < 2; ++n) {
        acc[m][n] = __builtin_amdgcn_mfma_f32_16x16x32_f16(ah[m], bh[n], acc[m][n], 0, 0, 0);
        acc[m][n] = __builtin_amdgcn_mfma_f32_16x16x32_f16(ah[m], bl[n], acc[m][n], 0, 0, 0);
        acc[m][n] = __builtin_amdgcn_mfma_f32_16x16x32_f16(al[m], bh[n], acc[m][n], 0, 0, 0);
      }
  }

  #pragma unroll
  for (int m = 0; m < 4; ++m) {
    int rbase = row0 + wr * 64 + m * 16 + lg * 4;
    #pragma unroll
    for (int n = 0; n < 2; ++n) {
      int gcol = col0 + wc * 32 + n * 16 + lr;
      float bb = za.bias ? za.bias[gcol] : 0.0f;
      #pragma unroll
      for (int rr = 0; rr < 4; ++rr) {
        long idx = (long)(rbase + rr) * 1024 + gcol;
        float v = acc[m][n][rr] + bb;
        if (za.Cf) {
          za.Cf[idx] = za.resid ? (za.resid[idx] + v) : v;
        } else {
          _Float16 hh = (_Float16)v;
          za.Ch[idx] = hh;
          za.Cl[idx] = (_Float16)(v - (float)hh);
        }
      }
    }
  }
}

// ---------------- flash attention: pre-split K/V^T, gload_lds staging --------
template<bool CAUSAL>
__global__ __launch_bounds__(256)
void attn_hl(const float* __restrict__ Q,
             const _Float16* __restrict__ Khg, const _Float16* __restrict__ Klg,
             const _Float16* __restrict__ Vhg, const _Float16* __restrict__ Vlg,
             _Float16* __restrict__ Oh, _Float16* __restrict__ Ol,
             const int* __restrict__ mask, const int* __restrict__ flags,
             int Sq, int Sk, float qscale) {
  int qt = blockIdx.x, bh = blockIdx.y;
  int b = bh >> 4, h = bh & 15;
  int tid = threadIdx.x, lane = tid & 63, w = tid >> 6;
  int lr = lane & 15, lg = lane >> 4;
  int q0 = qt * 64;
  int mf = (!CAUSAL && mask) ? flags[1] : 0;
  int swz = lr & 7;

  __shared__ _Float16 Kh_s[64 * 64], Kl_s[64 * 64];
  __shared__ _Float16 Vh_s[64 * 64], Vl_s[64 * 64];
  __shared__ _Float16 Psh[4][16][72], Psl[4][16][72];

  v8h qh[2], ql[2];
  {
    long qbase = ((long)(b * Sq + q0 + w * 16 + lr) * NH_ + h) * HD_;
    #pragma unroll
    for (int kk = 0; kk < 2; ++kk) {
      v4f f0 = *(const v4f*)&Q[qbase + kk * 32 + lg * 8];
      v4f f1 = *(const v4f*)&Q[qbase + kk * 32 + lg * 8 + 4];
      #pragma unroll
      for (int j = 0; j < 8; ++j) {
        float f = (j < 4 ? f0[j] : f1[j - 4]) * qscale;
        _Float16 hh = (_Float16)f;
        qh[kk][j] = hh;
        ql[kk][j] = (_Float16)(f - (float)hh);
      }
    }
  }
  v4f of[4] = {};
  float m4[4], l4[4];
  #pragma unroll
  for (int i = 0; i < 4; ++i) { m4[i] = -3e38f; l4[i] = 0.0f; }

  int nkt = CAUSAL ? (qt + 1) : (Sk >> 6);
  for (int kt = 0; kt < nkt; ++kt) {
    __syncthreads();
    // stage K (rows=key) and V^T (rows=d) with source chunk-XOR pre-swizzle
    #pragma unroll
    for (int i = 0; i < 2; ++i) {
      int c = w + i * 4;
      int v = c * 64 + lane;
      int row = v >> 3, c8 = v & 7;
      int sc = (c8 ^ (row & 7)) << 3;
      long kb = ((long)(b * Sk + kt * 64 + row) * NH_ + h) * HD_ + sc;
      g2l16(Khg + kb, (char*)Kh_s + c * 1024);
      g2l16(Klg + kb, (char*)Kl_s + c * 1024);
      long vb = ((long)(b * NH_ + h) * HD_ + row) * Sk + kt * 64 + sc;
      g2l16(Vhg + vb, (char*)Vh_s + c * 1024);
      g2l16(Vlg + vb, (char*)Vl_s + c * 1024);
    }
    __syncthreads();

    v4f sf[4] = {};
    #pragma unroll
    for (int kk = 0; kk < 2; ++kk)
      #pragma unroll
      for (int n = 0; n < 4; ++n) {
        int off = (n * 16 + lr) * 128 + ((((kk << 2) | lg) ^ swz) << 4);
        v8h kbh = *(const v8h*)((char*)Kh_s + off);
        v8h kbl = *(const v8h*)((char*)Kl_s + off);
        sf[n] = __builtin_amdgcn_mfma_f32_16x16x32_f16(qh[kk], kbh, sf[n], 0, 0, 0);
        sf[n] = __builtin_amdgcn_mfma_f32_16x16x32_f16(qh[kk], kbl, sf[n], 0, 0, 0);
        sf[n] = __builtin_amdgcn_mfma_f32_16x16x32_f16(ql[kk], kbh, sf[n], 0, 0, 0);
      }

    if constexpr (CAUSAL) {
      if (kt == qt) {
        #pragma unroll
        for (int n = 0; n < 4; ++n) {
          int kcol = kt * 64 + n * 16 + lr;
          #pragma unroll
          for (int rr = 0; rr < 4; ++rr) {
            int qr = q0 + w * 16 + lg * 4 + rr;
            if (kcol > qr) sf[n][rr] = -1e9f;
          }
        }
      }
    } else {
      if (mask) {
        #pragma unroll
        for (int n = 0; n < 4; ++n) {
          int kcol = kt * 64 + n * 16 + lr;
          int mi = b * Sk + kcol;
          if (mask[mf ? (mi << 1) : mi] == 0) {
            #pragma unroll
            for (int rr = 0; rr < 4; ++rr) sf[n][rr] = -1e9f;
          }
        }
      }
    }

    float al[4];
    #pragma unroll
    for (int rr = 0; rr < 4; ++rr) {
      float mx = fmaxf(fmaxf(sf[0][rr], sf[1][rr]), fmaxf(sf[2][rr], sf[3][rr]));
      #pragma unroll
      for (int off = 8; off; off >>= 1) mx = fmaxf(mx, __shfl_xor(mx, off));
      float mn = fmaxf(m4[rr], mx);
      al[rr] = __expf(m4[rr] - mn);
      m4[rr] = mn;
      float rs = 0.0f;
      #pragma unroll
      for (int n = 0; n < 4; ++n) {
        float pv = __expf(sf[n][rr] - mn);
        sf[n][rr] = pv;
        rs += pv;
      }
      #pragma unroll
      for (int off = 8; off; off >>= 1) rs += __shfl_xor(rs, off);
      l4[rr] = l4[rr] * al[rr] + rs;
    }

    #pragma unroll
    for (int n = 0; n < 4; ++n)
      #pragma unroll
      for (int rr = 0; rr < 4; ++rr) {
        of[n][rr] *= al[rr];
        float pv = sf[n][rr];
        _Float16 ph = (_Float16)pv;
        Psh[w][lg * 4 + rr][n * 16 + lr] = ph;
        Psl[w][lg * 4 + rr][n * 16 + lr] = (_Float16)(pv - (float)ph);
      }
    __syncthreads();

    #pragma unroll
    for (int kc = 0; kc < 2; ++kc) {
      v8h pah = *(const v8h*)&Psh[w][lr][kc * 32 + lg * 8];
      v8h pal = *(const v8h*)&Psl[w][lr][kc * 32 + lg * 8];
      #pragma unroll
      for (int n = 0; n < 4; ++n) {
        int off = (n * 16 + lr) * 128 + ((((kc << 2) | lg) ^ swz) << 4);
        v8h vbh = *(const v8h*)((char*)Vh_s + off);
        v8h vbl = *(const v8h*)((char*)Vl_s + off);
        of[n] = __builtin_amdgcn_mfma_f32_16x16x32_f16(pah, vbh, of[n], 0, 0, 0);
        of[n] = __builtin_amdgcn_mfma_f32_16x16x32_f16(pah, vbl, of[n], 0, 0, 0);
        of[n] = __builtin_amdgcn_mfma_f32_16x16x32_f16(pal, vbh, of[n], 0, 0, 0);
      }
    }
  }

  #pragma unroll
  for (int rr = 0; rr < 4; ++rr) {
    int qr = q0 + w * 16 + lg * 4 + rr;
    float inv = 1.0f / l4[rr];
    long ob = (long)(b * Sq + qr) * 1024 + h * 64;
    #pragma unroll
    for (int n = 0; n < 4; ++n) {
      float v = of[n][rr] * inv;
      _Float16 hh = (_Float16)v;
      Oh[ob + n * 16 + lr] = hh;
      Ol[ob + n * 16 + lr] = (_Float16)(v - (float)hh);
    }
  }
}

// ---------------- MoE GEMM1: 128x64 tile, dual-B swiglu, bf16 weights -------
__global__ __launch_bounds__(256)
void moe_gemm1(const unsigned short* __restrict__ A,
               const unsigned short* __restrict__ B1,
               const unsigned short* __restrict__ B2,
               unsigned short* __restrict__ Cb,
               const int* __restrict__ tm_e, const int* __restrict__ tm_slot,
               const int* __restrict__ ntl, const int* __restrict__ perm) {
  int tile = blockIdx.x;
  if (tile >= ntl[0]) return;
  int e = tm_e[tile];
  int row0 = tm_slot[tile];
  const unsigned short* Bp1 = B1 + (long)e * (FF_ * H_);
  const unsigned short* Bp2 = B2 + (long)e * (FF_ * H_);
  int col0 = blockIdx.y * 64;
  int tid = threadIdx.x, lane = tid & 63, w = tid >> 6;
  int lr = lane & 15, lg = lane >> 4;
  int wr = w >> 1, wc = w & 1;

  __shared__ unsigned short As[128 * 32];
  __shared__ unsigned short Bs1[64 * 32];
  __shared__ unsigned short Bs2[64 * 32];

  const unsigned short* ga[2];
  #pragma unroll
  for (int i = 0; i < 2; ++i) {
    int c = i * 256 + tid;
    int r = c >> 2, sub = c & 3;
    int tok = perm[row0 + r];
    ga[i] = A + (long)(tok < 0 ? 0 : tok) * H_ + sub * 8;
  }
  int rb = tid >> 2, subb = (tid & 3) * 8;
  const unsigned short* gb1 = Bp1 + (long)(col0 + rb) * H_ + subb;
  const unsigned short* gb2 = Bp2 + (long)(col0 + rb) * H_ + subb;

  v4f acc[4][2] = {};
  v4f acc2[4][2] = {};

  for (int k0 = 0; k0 < H_; k0 += 32) {
    __syncthreads();
    #pragma unroll
    for (int i = 0; i < 2; ++i)
      g2l16(ga[i] + k0, As + (size_t)(i * 256 + w * 64) * 8);
    g2l16(gb1 + k0, Bs1 + (size_t)(w * 64) * 8);
    g2l16(gb2 + k0, Bs2 + (size_t)(w * 64) * 8);
    __syncthreads();

    v8s a[4], b[2];
    #pragma unroll
    for (int m = 0; m < 4; ++m) a[m] = *(const v8s*)&As[(wr * 64 + m * 16 + lr) * 32 + lg * 8];
    #pragma unroll
    for (int n = 0; n < 2; ++n) b[n] = *(const v8s*)&Bs1[(wc * 32 + n * 16 + lr) * 32 + lg * 8];
    #pragma unroll
    for (int m = 0; m < 4; ++m)
      #pragma unroll
      for (int n = 0; n < 2; ++n)
        acc[m][n] = __builtin_amdgcn_mfma_f32_16x16x32_bf16(a[m], b[n], acc[m][n], 0, 0, 0);
    #pragma unroll
    for (int n = 0; n < 2; ++n) b[n] = *(const v8s*)&Bs2[(wc * 32 + n * 16 + lr) * 32 + lg * 8];
    #pragma unroll
    for (int m = 0; m < 4; ++m)
      #pragma unroll
      for (int n = 0; n < 2; ++n)
        acc2[m][n] = __builtin_amdgcn_mfma_f32_16x16x32_bf16(a[m], b[n], acc2[m][n], 0, 0, 0);
  }

  #pragma unroll
  for (int m = 0; m < 4; ++m) {
    int grow = row0 + wr * 64 + m * 16 + lg * 4;
    #pragma unroll
    for (int n = 0; n < 2; ++n) {
      int gcol = col0 + wc * 32 + n * 16 + lr;
      #pragma unroll
      for (int rr = 0; rr < 4; ++rr) {
        float v = acc[m][n][rr];
        float g = v / (1.0f + __expf(-v));
        Cb[(long)(grow + rr) * FF_ + gcol] = f2b(g * acc2[m][n][rr]);
      }
    }
  }
}

// ---------------- MoE GEMM2: 128x128 tile, scatter-accumulate ----------------
__global__ __launch_bounds__(256)
void moe_gemm2(const unsigned short* __restrict__ A,
               const unsigned short* __restrict__ B,
               float* __restrict__ Cf,
               const int* __restrict__ tm_e, const int* __restrict__ tm_slot,
               const int* __restrict__ ntl,
               const int* __restrict__ perm, const float* __restrict__ pwgt) {
  int tile = blockIdx.x;
  if (tile >= ntl[0]) return;
  int e = tm_e[tile];
  int row0 = tm_slot[tile];
  const unsigned short* Bp = B + (long)e * (H_ * FF_);
  int col0 = blockIdx.y * 128;
  int tid = threadIdx.x, lane = tid & 63, w = tid >> 6;
  int lr = lane & 15, lg = lane >> 4;
  int wr = w >> 1, wc = w & 1;

  __shared__ unsigned short As[128 * 32];
  __shared__ unsigned short Bs[128 * 32];

  const unsigned short* ga[2];
  const unsigned short* gb[2];
  #pragma unroll
  for (int i = 0; i < 2; ++i) {
    int c = i * 256 + tid;
    int r = c >> 2, sub = c & 3;
    ga[i] = A + (long)(row0 + r) * FF_ + sub * 8;
    gb[i] = Bp + (long)(col0 + r) * FF_ + sub * 8;
  }

  v4f acc[4][4] = {};

  for (int k0 = 0; k0 < FF_; k0 += 32) {
    __syncthreads();
    #pragma unroll
    for (int i = 0; i < 2; ++i) {
      g2l16(ga[i] + k0, As + (size_t)(i * 256 + w * 64) * 8);
      g2l16(gb[i] + k0, Bs + (size_t)(i * 256 + w * 64) * 8);
    }
    __syncthreads();

    v8s a[4], b[4];
    #pragma unroll
    for (int m = 0; m < 4; ++m) a[m] = *(const v8s*)&As[(wr * 64 + m * 16 + lr) * 32 + lg * 8];
    #pragma unroll
    for (int n = 0; n < 4; ++n) b[n] = *(const v8s*)&Bs[(wc * 64 + n * 16 + lr) * 32 + lg * 8];
    #pragma unroll
    for (int m = 0; m < 4; ++m)
      #pragma unroll
      for (int n = 0; n < 4; ++n)
        acc[m][n] = __builtin_amdgcn_mfma_f32_16x16x32_bf16(a[m], b[n], acc[m][n], 0, 0, 0);
  }

  #pragma unroll
  for (int m = 0; m < 4; ++m) {
    int grow = row0 + wr * 64 + m * 16 + lg * 4;
    #pragma unroll
    for (int rr = 0; rr < 4; ++rr) {
      int tok = perm[grow + rr];
      if (tok < 0) continue;
      float pw = pwgt[grow + rr];
      #pragma unroll
      for (int n = 0; n < 4; ++n) {
        int gcol = col0 + wc * 64 + n * 16 + lr;
        atomicAdd(&Cf[(long)tok * H_ + gcol], acc[m][n][rr] * pw);
      }
    }
  }
}

// ---------------- MoE router: f32 rms + logits + top-2 ----------------
__global__ __launch_bounds__(64)
void router_kern(const float* __restrict__ x, const float* __restrict__ w,
                 const float* __restrict__ gw,
                 int* __restrict__ topi, float* __restrict__ topw,
                 int* __restrict__ counts) {
  int t = blockIdx.x, lane = threadIdx.x;
  const float* xr = x + (long)t * 1024;
  float vals[16];
  float ss = 0.0f;
  #pragma unroll
  for (int i = 0; i < 16; ++i) { float v = xr[lane + i * 64]; vals[i] = v; ss += v * v; }
  #pragma unroll
  for (int off = 32; off; off >>= 1) ss += __shfl_xor(ss, off);
  float rs = rsqrtf(ss * (1.0f / 1024.0f) + 1e-6f);
  #pragma unroll
  for (int i = 0; i < 16; ++i) vals[i] *= rs * w[lane + i * 64];
  float lgts[8];
  #pragma unroll
  for (int e = 0; e < 8; ++e) {
    const float* g = gw + e * 1024;
    float s = 0.0f;
    #pragma unroll
    for (int i = 0; i < 16; ++i) s += vals[i] * g[lane + i * 64];
    #pragma unroll
    for (int off = 32; off; off >>= 1) s += __shfl_xor(s, off);
    lgts[e] = s;
  }
  int i1 = 0; float l1 = lgts[0];
  #pragma unroll
  for (int e = 1; e < 8; ++e) if (lgts[e] > l1) { l1 = lgts[e]; i1 = e; }
  int i2 = -1; float l2 = -3e38f;
  #pragma unroll
  for (int e = 0; e < 8; ++e) if (e != i1 && lgts[e] > l2) { l2 = lgts[e]; i2 = e; }
  float w1 = 1.0f / (1.0f + __expf(l2 - l1));
  if (lane == 0) {
    topi[t * 2] = i1; topi[t * 2 + 1] = i2;
    topw[t * 2] = w1; topw[t * 2 + 1] = 1.0f - w1;
    atomicAdd(&counts[i1], 1);
    atomicAdd(&counts[i2], 1);
  }
}

__global__ __launch_bounds__(256)
void finalize_kern(const int* __restrict__ counts, int* __restrict__ poff,
                   int* __restrict__ tm_e, int* __restrict__ tm_slot,
                   int* __restrict__ ntl, int* __restrict__ perm) {
  __shared__ int stot;
  if (threadIdx.x == 0) {
    int off = 0, nt = 0;
    for (int e = 0; e < 8; ++e) {
      poff[e] = off;
      int c = counts[e];
      int ntE = (c + 127) >> 7;
      for (int i = 0; i < ntE; ++i) { tm_e[nt] = e; tm_slot[nt] = off + i * 128; ++nt; }
      off += ntE * 128;
    }
    ntl[0] = nt; ntl[1] = off;
    stot = off;
  }
  __syncthreads();
  for (int s = threadIdx.x; s < stot; s += 256) perm[s] = -1;
}

__global__ __launch_bounds__(256)
void scatter_kern(const int* __restrict__ topi, const float* __restrict__ topw,
                  const int* __restrict__ poff, int* __restrict__ cursor,
                  int* __restrict__ perm, float* __restrict__ pwgt) {
  int t = blockIdx.x * 256 + threadIdx.x;
  if (t >= T_) return;
  #pragma unroll
  for (int kk = 0; kk < 2; ++kk) {
    int e = topi[t * 2 + kk];
    int pos = atomicAdd(&cursor[e], 1);
    int slot = poff[e] + pos;
    perm[slot] = t;
    pwgt[slot] = topw[t * 2 + kk];
  }
}

// ---------------- host launcher ----------------
extern "C" void kernel_launch(void* const* d_in, const int* in_sizes, int n_in,
                              void* d_out, int out_size, void* d_ws, size_t ws_size,
                              hipStream_t stream) {
  (void)in_sizes; (void)n_in; (void)out_size; (void)ws_size;
  const float* x_in  = (const float*)d_in[0];
  const int*  posids = (const int*)d_in[1];
  const float* enc   = (const float*)d_in[2];
  const int*  emask  = (const int*)d_in[3];
  const float* inln  = (const float*)d_in[4];
  const float* wq    = (const float*)d_in[5];
  const float* wk    = (const float*)d_in[6];
  const float* wv    = (const float*)d_in[7];
  const float* wo    = (const float*)d_in[8];
  const float* cnorm = (const float*)d_in[9];
  const float* cqw   = (const float*)d_in[10];
  const float* cqb   = (const float*)d_in[11];
  const float* ckw   = (const float*)d_in[12];
  const float* ckb   = (const float*)d_in[13];
  const float* cvw   = (const float*)d_in[14];
  const float* cvb   = (const float*)d_in[15];
  const float* cow   = (const float*)d_in[16];
  const float* cob   = (const float*)d_in[17];
  const float* pln   = (const float*)d_in[18];
  const float* gatew = (const float*)d_in[19];
  const float* w1    = (const float*)d_in[20];
  const float* w2    = (const float*)d_in[21];
  const float* w3    = (const float*)d_in[22];
  float* out = (float*)d_out;

  char* p = (char*)d_ws;
  auto alloc = [&](size_t bytes) -> char* {
    char* r = p;
    p += (bytes + 255) & ~(size_t)255;
    return r;
  };
  const size_t MB = 1024 * 1024;
  char* A1 = alloc(4 * MB);   // hh -> oh -> ckh
  char* A2 = alloc(4 * MB);   // hl -> ol -> ckl
  char* Bq = alloc(8 * MB);   // qf -> cqf -> ffh
  char* Bk = alloc(8 * MB);   // kf -> cvth/cvtl -> ffh
  char* Bv = alloc(8 * MB);   // vf -> cvf -> ffh
  char* C1 = alloc(4 * MB);   // kh -> h2h
  char* C2 = alloc(4 * MB);   // kl -> h2l
  char* D1 = alloc(4 * MB);   // vth -> coh
  char* D2 = alloc(4 * MB);   // vtl -> col
  float* x1 = (float*)alloc(8 * MB);
  float* x2 = (float*)alloc(8 * MB);
  unsigned short* h3b = (unsigned short*)alloc(4 * MB);
  _Float16* ench = (_Float16*)alloc(2 * MB);
  _Float16* encl = (_Float16*)alloc(2 * MB);
  int*   meta    = (int*)alloc(4 * (8 + 8 + 8 + 2 + 2 + MAXRT + MAXRT));
  int*   counts  = meta;
  int*   cursor  = meta + 8;
  int*   poff    = meta + 16;
  int*   ntl     = meta + 24;
  int*   flags   = meta + 26;
  int*   tm_e    = meta + 28;
  int*   tm_slot = meta + 28 + MAXRT;
  int*   topi    = (int*)alloc((size_t)T_ * 2 * 4);
  float* topw    = (float*)alloc((size_t)T_ * 2 * 4);
  int*   perm    = (int*)alloc((size_t)PERM_MAX * 4);
  float* pwgt    = (float*)alloc((size_t)PERM_MAX * 4);
  unsigned short* w1b = (unsigned short*)alloc((size_t)NEXP_ * FF_ * H_ * 2);  // 32 MB, also wsp
  unsigned short* w3b = (unsigned short*)alloc((size_t)NEXP_ * FF_ * H_ * 2);
  unsigned short* w2b = (unsigned short*)alloc((size_t)NEXP_ * H_ * FF_ * 2);

  // aliased views
  _Float16 *hh = (_Float16*)A1, *hl = (_Float16*)A2;
  _Float16 *oh = (_Float16*)A1, *ol = (_Float16*)A2;
  _Float16 *ckh = (_Float16*)A1, *ckl = (_Float16*)A2;
  float* qf = (float*)Bq;  float* cqf = (float*)Bq;
  float* kf = (float*)Bk;
  _Float16 *cvth = (_Float16*)Bk, *cvtl = (_Float16*)(Bk + 4 * MB);
  float* vf = (float*)Bv;  float* cvf = (float*)Bv;
  _Float16 *kh = (_Float16*)C1, *kl = (_Float16*)C2;
  _Float16 *h2h = (_Float16*)C1, *h2l = (_Float16*)C2;
  _Float16 *vth = (_Float16*)D1, *vtl = (_Float16*)D2;
  _Float16 *coh = (_Float16*)D1, *col = (_Float16*)D2;
  unsigned short* ffh = (unsigned short*)Bq;   // spans Bq..Bv (24 MB > 20.9 needed)
  // split weights live in w1b/w3b region until MoE cvt (launched after last use)
  _Float16* wsp = (_Float16*)w1b;
  auto wsph = [&](int i) { return wsp + (size_t)i * 2097152; };
  auto wspl = [&](int i) { return wsp + (size_t)i * 2097152 + 1048576; };

  dim3 blk(256);
  const int WN8 = H_ * H_ / 8;   // 131072

  detect_kern<<<1, 64, 0, stream>>>(posids, emask, flags);

  // pre-split attention weights + encoder states
  const float* wlist[8] = {wq, wk, wv, wo, cqw, ckw, cvw, cow};
  for (int i = 0; i < 8; ++i)
    split_kern<<<(WN8 + 255) / 256, blk, 0, stream>>>(wlist[i], wsph(i), wspl(i), WN8);
  split_kern<<<(TE_ * E_ / 8 + 255) / 256, blk, 0, stream>>>(enc, ench, encl, TE_ * E_ / 8);

  // ---- self-attention block ----
  rmsnorm_hl_kern<<<T_, blk, 0, stream>>>(x_in, inln, hh, hl);
  {
    ZArg zq = {hh, hl, wsph(0), wspl(0), nullptr, nullptr, qf, nullptr, nullptr, 2048};
    ZArg zk = {hh, hl, wsph(1), wspl(1), nullptr, nullptr, kf, nullptr, nullptr, 2048};
    ZArg zv = {hh, hl, wsph(2), wspl(2), nullptr, nullptr, vf, nullptr, nullptr, 2048};
    gemm_hl<<<dim3(16, 16, 3), blk, 0, stream>>>(zq, zk, zv, 1024);
  }
  rope_split_kern<<<(B_ * S_ * NH_ * 32) / 256, blk, 0, stream>>>(qf, kf, kh, kl, posids, flags);
  vtrans_kern<<<dim3(16, 32), blk, 0, stream>>>(vf, vth, vtl, 1024);
  attn_hl<true><<<dim3(16, 32), blk, 0, stream>>>(
      qf, kh, kl, vth, vtl, oh, ol, nullptr, flags, 1024, 1024, 0.125f);
  {
    ZArg zo = {oh, ol, wsph(3), wspl(3), nullptr, x_in, x1, nullptr, nullptr, 2048};
    gemm_hl<<<dim3(16, 16, 1), blk, 0, stream>>>(zo, zo, zo, 1024);
  }

  // ---- cross-attention block ----
  rmsnorm_hl_kern<<<T_, blk, 0, stream>>>(x1, cnorm, h2h, h2l);
  {
    ZArg zcq = {h2h, h2l, wsph(4), wspl(4), cqb, nullptr, cqf, nullptr, nullptr, 2048};
    ZArg zck = {ench, encl, wsph(5), wspl(5), ckb, nullptr, nullptr, ckh, ckl, 1024};
    ZArg zcv = {ench, encl, wsph(6), wspl(6), cvb, nullptr, cvf, nullptr, nullptr, 1024};
    gemm_hl<<<dim3(16, 16, 3), blk, 0, stream>>>(zcq, zck, zcv, 1024);
  }
  vtrans_kern<<<dim3(8, 32), blk, 0, stream>>>(cvf, cvth, cvtl, 512);
  attn_hl<false><<<dim3(16, 32), blk, 0, stream>>>(
      cqf, ckh, ckl, cvth, cvtl, coh, col, emask, flags, 1024, 512, 0.125f);
  {
    ZArg zco = {coh, col, wsph(7), wspl(7), cob, x1, x2, nullptr, nullptr, 2048};
    gemm_hl<<<dim3(16, 16, 1), blk, 0, stream>>>(zco, zco, zco, 1024);
  }

  // ---- MoE block (weight cvts after last wsp use; stream is serial) ----
  cvt_kern<<<(NEXP_ * FF_ * H_ / 4 + 255) / 256, blk, 0, stream>>>(w1, w1b, NEXP_ * FF_ * H_ / 4);
  cvt_kern<<<(NEXP_ * FF_ * H_ / 4 + 255) / 256, blk, 0, stream>>>(w3, w3b, NEXP_ * FF_ * H_ / 4);
  cvt_kern<<<(NEXP_ * H_ * FF_ / 4 + 255) / 256, blk, 0, stream>>>(w2, w2b, NEXP_ * H_ * FF_ / 4);
  rmsnorm_kern<<<T_, blk, 0, stream>>>(x2, pln, h3b);
  hipMemsetAsync(meta, 0, 64, stream);   // counts + cursor
  router_kern<<<T_, dim3(64), 0, stream>>>(x2, pln, gatew, topi, topw, counts);
  finalize_kern<<<1, blk, 0, stream>>>(counts, poff, tm_e, tm_slot, ntl, perm);
  scatter_kern<<<(T_ + 255) / 256, blk, 0, stream>>>(topi, topw, poff, cursor, perm, pwgt);
  moe_gemm1<<<dim3(MAXRT, FF_ / 64), blk, 0, stream>>>(
      h3b, w1b, w3b, ffh, tm_e, tm_slot, ntl, perm);
  hipMemcpyAsync(out, x2, (size_t)T_ * H_ * 4, hipMemcpyDeviceToDevice, stream);
  moe_gemm2<<<dim3(MAXRT, H_ / 128), blk, 0, stream>>>(
      ffh, w2b, out, tm_e, tm_slot, ntl, perm, pwgt);
}